// Round 6
// baseline (137.480 us; speedup 1.0000x reference)
//
#include <hip/hip_runtime.h>
#include <cmath>

typedef unsigned short u16;
typedef unsigned short u16x4 __attribute__((ext_vector_type(4)));
typedef unsigned short u16x8 __attribute__((ext_vector_type(8)));
typedef __bf16 bf16x8 __attribute__((ext_vector_type(8)));
typedef float f32x4 __attribute__((ext_vector_type(4)));

#define HNUM 8
#define HDIM 64
#define BATCH 4
#define NSEQ 2048
#define DMODEL 512
#define LP 72   // padded LDS row stride in u16 (144 B) for the attn kernel

__device__ __forceinline__ u16 f2bf(float f) {
  unsigned int u = __builtin_bit_cast(unsigned int, f);
  u += 0x7fffu + ((u >> 16) & 1u);          // round-to-nearest-even
  return (u16)(u >> 16);
}

__device__ __forceinline__ float bf2f(u16 v) {
  unsigned int u = ((unsigned int)v) << 16;
  return __builtin_bit_cast(float, u);
}

__device__ __forceinline__ f32x4 mfma_bf16(u16x8 a, u16x8 b, f32x4 c) {
  return __builtin_amdgcn_mfma_f32_16x16x32_bf16(
      __builtin_bit_cast(bf16x8, a), __builtin_bit_cast(bf16x8, b), c, 0, 0, 0);
}

// async global->LDS, 16 B per lane (dest must be wave-uniform base + lane*16)
__device__ __forceinline__ void gload16(u16* lds, const u16* g) {
  __builtin_amdgcn_global_load_lds(
      (const __attribute__((address_space(1))) void*)g,
      (__attribute__((address_space(3))) void*)lds, 16, 0, 0);
}

// stage a ROWS x 32 bf16 tile (row stride DMODEL) into linear LDS
template <int ROWS>
__device__ __forceinline__ void stage_tile(u16* lds, const u16* g, int tid) {
  #pragma unroll
  for (int i = 0; i < ROWS / 64; ++i) {
    const int off = (i * 256 + tid) * 8;
    const int row = off >> 5, col = off & 31;
    gload16(lds + off, g + (size_t)row * DMODEL + col);
  }
}

// ---------------------------------------------------------------------------
// Prep: fp32 -> bf16 convert (x), 8 elems/thread
// ---------------------------------------------------------------------------
__global__ __launch_bounds__(256) void cvt_bf16_kernel(
    const float* __restrict__ in, u16* __restrict__ out, int n8) {
  int i = blockIdx.x * 256 + threadIdx.x;
  if (i >= n8) return;
  const float4 f0 = *(const float4*)(in + i * 8);
  const float4 f1 = *(const float4*)(in + i * 8 + 4);
  u16x8 pk;
  pk[0] = f2bf(f0.x); pk[1] = f2bf(f0.y); pk[2] = f2bf(f0.z); pk[3] = f2bf(f0.w);
  pk[4] = f2bf(f1.x); pk[5] = f2bf(f1.y); pk[6] = f2bf(f1.z); pk[7] = f2bf(f1.w);
  *(u16x8*)(out + i * 8) = pk;
}

// ---------------------------------------------------------------------------
// Prep: W[K][N] fp32 -> Wt[N][K] bf16 (32x32 LDS tile transpose)
// ---------------------------------------------------------------------------
__global__ __launch_bounds__(256) void transpose_w_kernel(
    const float* __restrict__ W, u16* __restrict__ Wt, int K, int N) {
  __shared__ float tile[32][33];
  const int n0 = blockIdx.x * 32, k0 = blockIdx.y * 32;
  const int tx = threadIdx.x & 31, ty = threadIdx.x >> 5;
  #pragma unroll
  for (int yy = ty; yy < 32; yy += 8)
    tile[yy][tx] = W[(size_t)(k0 + yy) * N + n0 + tx];
  __syncthreads();
  #pragma unroll
  for (int yy = ty; yy < 32; yy += 8)
    Wt[(size_t)(n0 + yy) * K + k0 + tx] = f2bf(tile[tx][yy]);
}

// ---------------------------------------------------------------------------
// Prep: vbf[b,h,n,d] -> vbfT[b,h,d,n] (64x64 LDS tile transpose)
// ---------------------------------------------------------------------------
__global__ __launch_bounds__(256) void transpose_v_kernel(
    const u16* __restrict__ v, u16* __restrict__ vT) {
  __shared__ u16 t[64][LP];
  const int n0 = blockIdx.x * 64;
  const size_t bh = blockIdx.y;
  const int r = threadIdx.x >> 2, c0 = (threadIdx.x & 3) << 4;
  const u16* src = v + (bh * NSEQ + n0 + r) * HDIM + c0;
  u16x8 a0 = *(const u16x8*)src;
  u16x8 a1 = *(const u16x8*)(src + 8);
  #pragma unroll
  for (int j = 0; j < 8; ++j) {
    t[c0 + j][r] = a0[j];
    t[c0 + 8 + j][r] = a1[j];
  }
  __syncthreads();
  u16x8 o0 = *(const u16x8*)&t[r][c0];
  u16x8 o1 = *(const u16x8*)&t[r][c0 + 8];
  u16* dst = vT + (bh * HDIM + r) * NSEQ + n0 + c0;
  *(u16x8*)dst = o0;
  *(u16x8*)(dst + 8) = o1;
}

// ---------------------------------------------------------------------------
// Bias table: tab[h][d] = in_band(bucket(d),h) ? pos_bias[bucket(d)][h] : -100
// ---------------------------------------------------------------------------
__global__ __launch_bounds__(256) void bias_tab_kernel(
    const float* __restrict__ pos_bias, float* __restrict__ tab) {
  int d = blockIdx.x * 256 + threadIdx.x;   // 0..2047
  if (d >= NSEQ) return;
  int bkt;
  if (d < 28) {
    bkt = d;
  } else {
    double t = log((double)d / 28.0) / log(2048.0 / 28.0) * 16.0;
    int ti = 28 + (int)t;
    bkt = ti < 43 ? ti : 43;
  }
  const int lo[8] = {38, 34, 28, 20, 13, 7, 3, 0};
  const int hi[8] = {44, 40, 35, 28, 21, 14, 9, 6};
  #pragma unroll
  for (int h = 0; h < HNUM; ++h) {
    bool inb = (bkt >= lo[h]) && (bkt < hi[h]);
    tab[h * NSEQ + d] = inb ? pos_bias[bkt * HNUM + h] : -100.0f;
  }
}

// ---------------------------------------------------------------------------
// Fused qkv+gate GEMM: [8192,512]bf16 @ Wt[2048,512]^T, 128x128 tile, BK=32,
// double-buffered global_load_lds staging (2-phase pipeline).
// Col groups: 0=q (*0.125), 1=k (+kdelta), 2=v (+vdelta, row-major),
//             3=gate (sigmoid).
// ---------------------------------------------------------------------------
__global__ __launch_bounds__(256) void gemm_qkvg(
    const u16* __restrict__ Abf, const u16* __restrict__ Wt,
    const float* __restrict__ qkv_b, const float* __restrict__ gate_b,
    const float* __restrict__ kdelta, const float* __restrict__ vdelta,
    u16* __restrict__ qbf, u16* __restrict__ kbf, u16* __restrict__ vbf,
    u16* __restrict__ gate_buf) {
  __shared__ __align__(16) u16 As[2][128 * 32];
  __shared__ __align__(16) u16 Bs[2][128 * 32];

  const int m0 = blockIdx.y * 128, n0 = blockIdx.x * 128;
  const int tid = threadIdx.x;
  const int w = tid >> 6, l = tid & 63, li = l & 15, lg = l >> 4;
  const int wr = w >> 1, wc = w & 1;

  f32x4 acc[4][4];
  #pragma unroll
  for (int i = 0; i < 4; ++i)
    #pragma unroll
    for (int j = 0; j < 4; ++j) acc[i][j] = f32x4{0.f, 0.f, 0.f, 0.f};

  const u16* Ab = Abf + (size_t)m0 * DMODEL;
  const u16* Bb = Wt + (size_t)n0 * DMODEL;
  stage_tile<128>(As[0], Ab, tid);
  stage_tile<128>(Bs[0], Bb, tid);
  __syncthreads();

  int cur = 0;
  for (int kt = 0; kt < 16; ++kt) {
    if (kt < 15) {
      stage_tile<128>(As[cur ^ 1], Ab + (kt + 1) * 32, tid);
      stage_tile<128>(Bs[cur ^ 1], Bb + (kt + 1) * 32, tid);
    }
    u16x8 af[4], bfr[4];
    #pragma unroll
    for (int mt = 0; mt < 4; ++mt)
      af[mt] = *(const u16x8*)&As[cur][(wr * 64 + mt * 16 + li) * 32 + lg * 8];
    #pragma unroll
    for (int nt = 0; nt < 4; ++nt)
      bfr[nt] = *(const u16x8*)&Bs[cur][(wc * 64 + nt * 16 + li) * 32 + lg * 8];
    #pragma unroll
    for (int mt = 0; mt < 4; ++mt)
      #pragma unroll
      for (int nt = 0; nt < 4; ++nt)
        acc[mt][nt] = mfma_bf16(af[mt], bfr[nt], acc[mt][nt]);
    __syncthreads();
    cur ^= 1;
  }

  // epilogue: row = m0+wr*64+mt*16+lg*4+r ; col = n0+wc*64+nt*16+li
  #pragma unroll
  for (int nt = 0; nt < 4; ++nt) {
    const int colg = n0 + wc * 64 + nt * 16 + li;
    const int which = colg >> 9;            // uniform per block (128 | 512)
    const int inner = colg & 511;
    const float bv = (which < 3) ? qkv_b[colg] : gate_b[inner];
    const int hh = inner >> 6, hd = inner & 63;
    #pragma unroll
    for (int mt = 0; mt < 4; ++mt) {
      const int rowbase = m0 + wr * 64 + mt * 16 + lg * 4;
      const int bb = rowbase >> 11, nn0 = rowbase & 2047;
      const size_t idx0 = (((size_t)bb * HNUM + hh) * NSEQ + nn0) * HDIM + hd;
      #pragma unroll
      for (int r = 0; r < 4; ++r) {
        const float val = acc[mt][nt][r] + bv;
        if (which == 0)
          qbf[idx0 + r * HDIM] = f2bf(val * 0.125f);       // fold 1/sqrt(HD)
        else if (which == 1)
          kbf[idx0 + r * HDIM] = f2bf(val + kdelta[idx0 + r * HDIM]);
        else if (which == 2)
          vbf[idx0 + r * HDIM] = f2bf(val + vdelta[idx0 + r * HDIM]);
        else
          gate_buf[(size_t)(rowbase + r) * DMODEL + inner] =
              f2bf(1.f / (1.f + __expf(-val)));
      }
    }
  }
}

// ---------------------------------------------------------------------------
// Out GEMM: [8192,512]bf16 @ out_wt[512,512]^T + out_b -> fp32. 64x128 tile,
// BK=32, double-buffered. Grid (4,128) = 512 blocks.
// ---------------------------------------------------------------------------
__global__ __launch_bounds__(256) void gemm_out(
    const u16* __restrict__ Abf, const u16* __restrict__ Wt,
    const float* __restrict__ bias, float* __restrict__ outf) {
  __shared__ __align__(16) u16 As[2][64 * 32];
  __shared__ __align__(16) u16 Bs[2][128 * 32];

  const int m0 = blockIdx.y * 64, n0 = blockIdx.x * 128;
  const int tid = threadIdx.x;
  const int w = tid >> 6, l = tid & 63, li = l & 15, lg = l >> 4;
  const int wr = w >> 1, wc = w & 1;

  f32x4 acc[2][4];
  #pragma unroll
  for (int i = 0; i < 2; ++i)
    #pragma unroll
    for (int j = 0; j < 4; ++j) acc[i][j] = f32x4{0.f, 0.f, 0.f, 0.f};

  const u16* Ab = Abf + (size_t)m0 * DMODEL;
  const u16* Bb = Wt + (size_t)n0 * DMODEL;
  stage_tile<64>(As[0], Ab, tid);
  stage_tile<128>(Bs[0], Bb, tid);
  __syncthreads();

  int cur = 0;
  for (int kt = 0; kt < 16; ++kt) {
    if (kt < 15) {
      stage_tile<64>(As[cur ^ 1], Ab + (kt + 1) * 32, tid);
      stage_tile<128>(Bs[cur ^ 1], Bb + (kt + 1) * 32, tid);
    }
    u16x8 af[2], bfr[4];
    #pragma unroll
    for (int mt = 0; mt < 2; ++mt)
      af[mt] = *(const u16x8*)&As[cur][(wr * 32 + mt * 16 + li) * 32 + lg * 8];
    #pragma unroll
    for (int nt = 0; nt < 4; ++nt)
      bfr[nt] = *(const u16x8*)&Bs[cur][(wc * 64 + nt * 16 + li) * 32 + lg * 8];
    #pragma unroll
    for (int mt = 0; mt < 2; ++mt)
      #pragma unroll
      for (int nt = 0; nt < 4; ++nt)
        acc[mt][nt] = mfma_bf16(af[mt], bfr[nt], acc[mt][nt]);
    __syncthreads();
    cur ^= 1;
  }

  #pragma unroll
  for (int nt = 0; nt < 4; ++nt) {
    const int colg = n0 + wc * 64 + nt * 16 + li;
    const float bv = bias[colg];
    #pragma unroll
    for (int mt = 0; mt < 2; ++mt) {
      #pragma unroll
      for (int r = 0; r < 4; ++r) {
        const int rowg = m0 + wr * 32 + mt * 16 + lg * 4 + r;
        outf[(size_t)rowg * DMODEL + colg] = acc[mt][nt][r] + bv;
      }
    }
  }
}

// ---------------------------------------------------------------------------
// Flash attention, swapped-QK^T, banded KV windows, split-KV balanced chunks.
// (verified round-5 body, unchanged)
// ---------------------------------------------------------------------------
__global__ __launch_bounds__(256) void attn_kernel(
    const u16* __restrict__ qbf, const u16* __restrict__ kbf,
    const u16* __restrict__ vbfT, const float* __restrict__ bias_tab,
    const float* __restrict__ if_gain, const u16* __restrict__ gate,
    u16* __restrict__ attn_out, u16* __restrict__ partO,
    float* __restrict__ partM, float* __restrict__ partL) {
  __shared__ __align__(16) u16 Ks[64][LP];   // [kv][hd]
  __shared__ __align__(16) u16 Vt[64][LP];   // [hd][kv]
  __shared__ __align__(16) u16 Pl[4][16][LP];

  static const int DMINW[8] = {408, 139, 26, 18, 11, 5, 1, 0};
  static const int DMAXW[8] = {2049, 702, 185, 29, 22, 15, 10, 7};
  static const int DMINS[8] = {412, 143, 30, 22, 15, 9, 5, 2};
  static const int SH[12] = {0, 0, 0, 0, 1, 1, 2, 3, 4, 5, 6, 7};
  static const int SC[12] = {0, 1, 2, 3, 0, 1, 0, 0, 0, 0, 0, 0};
  static const int SN[12] = {4, 4, 4, 4, 2, 2, 1, 1, 1, 1, 1, 1};

  const int slot = blockIdx.x >> 7;
  const int rem = blockIdx.x & 127;
  const int qt = 31 - (rem >> 2);
  const int b = rem & 3;
  const int h = SH[slot], ch = SC[slot], nc = SN[slot];
  const int bh = b * HNUM + h;
  const int q0 = qt * 64;
  const int tid = threadIdx.x;
  const int w = tid >> 6, l = tid & 63, li = l & 15, lg = l >> 4;

  const u16* qrow = qbf + ((size_t)bh * NSEQ + q0 + w * 16 + li) * HDIM;
  u16x8 qf0 = *(const u16x8*)(qrow + lg * 8);
  u16x8 qf1 = *(const u16x8*)(qrow + 32 + lg * 8);

  const bool pure = q0 >= DMINS[h];
  int kv_lo = 0, kv_hi = q0 + 64;
  if (pure) {
    int lo = q0 - DMAXW[h];
    kv_lo = (lo > 0 ? lo : 0) & ~63;
    kv_hi = q0 + 64 - DMINW[h];
  }
  const int t0 = kv_lo >> 6, t1 = (kv_hi - 1) >> 6;
  const int len = t1 - t0 + 1;
  const int ta = t0 + (len * ch) / nc;
  const int tb = t0 + (len * (ch + 1)) / nc - 1;

  const int srow = tid >> 2;
  const int scb = (tid & 3) << 4;
  const float* btab = bias_tab + h * NSEQ;

  float mrun = -INFINITY, lrun = 0.f;
  f32x4 O[4] = {{0.f,0.f,0.f,0.f},{0.f,0.f,0.f,0.f},
                {0.f,0.f,0.f,0.f},{0.f,0.f,0.f,0.f}};

  for (int tt = ta; tt <= tb; ++tt) {
    const int kv0 = tt << 6;
    {
      const size_t kbase = ((size_t)bh * NSEQ + kv0 + srow) * HDIM + scb;
      u16x8 k0 = *(const u16x8*)(kbf + kbase);
      u16x8 k1 = *(const u16x8*)(kbf + kbase + 8);
      const size_t vbase = ((size_t)bh * HDIM + srow) * NSEQ + kv0 + scb;
      u16x8 v0 = *(const u16x8*)(vbfT + vbase);
      u16x8 v1 = *(const u16x8*)(vbfT + vbase + 8);
      *(u16x8*)&Ks[srow][scb] = k0;
      *(u16x8*)&Ks[srow][scb + 8] = k1;
      *(u16x8*)&Vt[srow][scb] = v0;
      *(u16x8*)&Vt[srow][scb + 8] = v1;
    }
    __syncthreads();

    f32x4 s[4];
    #pragma unroll
    for (int t = 0; t < 4; ++t) {
      u16x8 a0 = *(const u16x8*)&Ks[t * 16 + li][lg * 8];
      u16x8 a1 = *(const u16x8*)&Ks[t * 16 + li][32 + lg * 8];
      f32x4 acc = {0.f, 0.f, 0.f, 0.f};
      acc = mfma_bf16(a0, qf0, acc);
      acc = mfma_bf16(a1, qf1, acc);
      s[t] = acc;
    }

    const int D0 = (q0 + w * 16 + li) - kv0 - lg * 4;
    float rm = -1e30f;
    #pragma unroll
    for (int t = 0; t < 4; ++t) {
      #pragma unroll
      for (int r = 0; r < 4; ++r) {
        int d = D0 - 16 * t - r;
        float sv = s[t][r];
        sv = (d >= 0) ? (sv + btab[d]) : -1e30f;
        s[t][r] = sv;
        rm = fmaxf(rm, sv);
      }
    }
    rm = fmaxf(rm, __shfl_xor(rm, 16, 64));
    rm = fmaxf(rm, __shfl_xor(rm, 32, 64));
    const float mn = fmaxf(mrun, rm);
    const float f = __expf(mrun - mn);
    mrun = mn;
    float ps = 0.f;
    #pragma unroll
    for (int t = 0; t < 4; ++t) {
      #pragma unroll
      for (int r = 0; r < 4; ++r) {
        float p = __expf(s[t][r] - mn);
        s[t][r] = p;
        ps += p;
      }
    }
    ps += __shfl_xor(ps, 16, 64);
    ps += __shfl_xor(ps, 32, 64);
    lrun = lrun * f + ps;

    #pragma unroll
    for (int t = 0; t < 4; ++t) {
      u16x4 pk;
      pk[0] = f2bf(s[t][0]); pk[1] = f2bf(s[t][1]);
      pk[2] = f2bf(s[t][2]); pk[3] = f2bf(s[t][3]);
      *(u16x4*)&Pl[w][li][t * 16 + lg * 4] = pk;
    }

    float fr[4];
    #pragma unroll
    for (int r = 0; r < 4; ++r) fr[r] = __shfl(f, lg * 4 + r, 64);
    #pragma unroll
    for (int dt = 0; dt < 4; ++dt) {
      O[dt][0] *= fr[0]; O[dt][1] *= fr[1];
      O[dt][2] *= fr[2]; O[dt][3] *= fr[3];
    }
    __syncthreads();

    #pragma unroll
    for (int ks = 0; ks < 2; ++ks) {
      u16x8 pA = *(const u16x8*)&Pl[w][li][ks * 32 + lg * 8];
      #pragma unroll
      for (int dt = 0; dt < 4; ++dt) {
        u16x8 vB = *(const u16x8*)&Vt[dt * 16 + li][ks * 32 + lg * 8];
        O[dt] = mfma_bf16(pA, vB, O[dt]);
      }
    }
    __syncthreads();
  }

  if (nc == 1) {
    const float gain = if_gain[h];
    float linv[4];
    #pragma unroll
    for (int r = 0; r < 4; ++r)
      linv[r] = gain / __shfl(lrun, lg * 4 + r, 64);
    #pragma unroll
    for (int r = 0; r < 4; ++r) {
      const int i = q0 + w * 16 + lg * 4 + r;
      const size_t base = ((size_t)b * NSEQ + i) * DMODEL + h * HDIM + li;
      #pragma unroll
      for (int dt = 0; dt < 4; ++dt) {
        const float g = bf2f(gate[base + dt * 16]);
        attn_out[base + dt * 16] = f2bf(O[dt][r] * linv[r] * g);
      }
    }
  } else {
    const int sbase = (b * 32 + qt) * 6 + slot;   // slot in 0..5 here
    #pragma unroll
    for (int r = 0; r < 4; ++r) {
      const int rl = w * 16 + lg * 4 + r;
      #pragma unroll
      for (int dt = 0; dt < 4; ++dt)
        partO[(size_t)sbase * 4096 + rl * 64 + dt * 16 + li] = f2bf(O[dt][r]);
    }
    if (lg == 0) {
      partM[sbase * 64 + w * 16 + li] = mrun;
      partL[sbase * 64 + w * 16 + li] = lrun;
    }
  }
}

// ---------------------------------------------------------------------------
// Combine split-KV partials for h0 (4 chunks) and h1 (2 chunks).
// ---------------------------------------------------------------------------
__global__ __launch_bounds__(256) void combine_kernel(
    const u16* __restrict__ partO, const float* __restrict__ partM,
    const float* __restrict__ partL, const float* __restrict__ if_gain,
    const u16* __restrict__ gate, u16* __restrict__ attn_out) {
  const int b = blockIdx.x & 3, qt = blockIdx.x >> 2;
  const int tid = threadIdx.x;
  const int row = tid >> 2, d0 = (tid & 3) << 4;

  #pragma unroll
  for (int hc = 0; hc < 2; ++hc) {
    const int nc = hc ? 2 : 4, s0 = hc ? 4 : 0;
    const int sbase = (b * 32 + qt) * 6 + s0;
    float m[4], wch[4];
    float M = -INFINITY;
    #pragma unroll
    for (int c = 0; c < 4; ++c) {
      m[c] = (c < nc) ? partM[(sbase + c) * 64 + row] : -INFINITY;
      M = fmaxf(M, m[c]);
    }
    float den = 0.f;
    #pragma unroll
    for (int c = 0; c < 4; ++c) {
      wch[c] = (c < nc) ? __expf(m[c] - M) : 0.f;
      if (c < nc) den += wch[c] * partL[(sbase + c) * 64 + row];
    }
    float num[16];
    #pragma unroll
    for (int j = 0; j < 16; ++j) num[j] = 0.f;
    #pragma unroll
    for (int c = 0; c < 4; ++c) {
      if (c < nc) {
        const u16* op = partO + (size_t)(sbase + c) * 4096 + row * 64 + d0;
        u16x8 o0 = *(const u16x8*)op;
        u16x8 o1 = *(const u16x8*)(op + 8);
        #pragma unroll
        for (int j = 0; j < 8; ++j) {
          num[j]     += wch[c] * bf2f(o0[j]);
          num[8 + j] += wch[c] * bf2f(o1[j]);
        }
      }
    }
    const float inv = if_gain[hc] / den;
    const size_t obase =
        ((size_t)b * NSEQ + qt * 64 + row) * DMODEL + hc * HDIM + d0;
    u16x8 g0 = *(const u16x8*)(gate + obase);
    u16x8 g1 = *(const u16x8*)(gate + obase + 8);
    u16x8 r0, r1;
    #pragma unroll
    for (int j = 0; j < 8; ++j) {
      r0[j] = f2bf(num[j] * inv * bf2f(g0[j]));
      r1[j] = f2bf(num[8 + j] * inv * bf2f(g1[j]));
    }
    *(u16x8*)(attn_out + obase) = r0;
    *(u16x8*)(attn_out + obase + 8) = r1;
  }
}

// ---------------------------------------------------------------------------
extern "C" void kernel_launch(void* const* d_in, const int* in_sizes, int n_in,
                              void* d_out, int out_size, void* d_ws,
                              size_t ws_size, hipStream_t stream) {
  const float* x       = (const float*)d_in[0];
  const float* k_delta = (const float*)d_in[1];
  const float* v_delta = (const float*)d_in[2];
  const float* qkv_w   = (const float*)d_in[3];
  const float* qkv_b   = (const float*)d_in[4];
  const float* gate_w  = (const float*)d_in[5];
  const float* gate_b  = (const float*)d_in[6];
  const float* out_w   = (const float*)d_in[7];
  const float* out_b   = (const float*)d_in[8];
  const float* pos_bias = (const float*)d_in[9];
  const float* if_gain  = (const float*)d_in[10];
  float* out = (float*)d_out;
  char* ws = (char*)d_ws;

  // workspace layout (bytes)
  u16*   xbf      = (u16*)(ws + 0);              // 8,388,608 (dead after gemm)
  u16*   qbf      = (u16*)(ws + 8388608);        // 8,388,608
  u16*   kbf      = (u16*)(ws + 16777216);       // 8,388,608
  u16*   vbf      = (u16*)(ws + 25165824);       // 8,388,608 (dead after v-T)
  u16*   vbfT     = (u16*)(ws + 33554432);       // 8,388,608
  u16*   gate_buf = (u16*)(ws + 41943040);       // 8,388,608
  u16*   fused_wt = (u16*)(ws + 50331648);       // 2,097,152
  u16*   out_wt   = (u16*)(ws + 52428800);       //   524,288
  float* bias_tab = (float*)(ws + 52953088);     //    65,536
  // aliases (stream-ordered safe):
  u16*   attn_buf = vbf;                         // vbf dead after transpose_v
  u16*   partO = (u16*)(ws + 0);                 // xbf dead after gemm_qkvg
  float* partM = (float*)(ws + 6291456);
  float* partL = (float*)(ws + 6488064);

  // prep
  cvt_bf16_kernel<<<dim3(2048), dim3(256), 0, stream>>>(
      x, xbf, BATCH * NSEQ * DMODEL / 8);
  transpose_w_kernel<<<dim3(48, 16), dim3(256), 0, stream>>>(
      qkv_w, fused_wt, DMODEL, 3 * DMODEL);
  transpose_w_kernel<<<dim3(16, 16), dim3(256), 0, stream>>>(
      gate_w, fused_wt + (size_t)3 * DMODEL * DMODEL, DMODEL, DMODEL);
  transpose_w_kernel<<<dim3(16, 16), dim3(256), 0, stream>>>(
      out_w, out_wt, DMODEL, DMODEL);
  bias_tab_kernel<<<dim3(8), dim3(256), 0, stream>>>(pos_bias, bias_tab);

  // fused qkv+gate GEMM (v row-major)
  gemm_qkvg<<<dim3(16, 64), dim3(256), 0, stream>>>(
      xbf, fused_wt, qkv_b, gate_b, k_delta, v_delta,
      qbf, kbf, vbf, gate_buf);

  // v -> v^T
  transpose_v_kernel<<<dim3(32, 32), dim3(256), 0, stream>>>(vbf, vbfT);

  // flash attention: split-KV balanced chunks
  attn_kernel<<<dim3(1536), dim3(256), 0, stream>>>(
      qbf, kbf, vbfT, bias_tab, if_gain, gate_buf, attn_buf,
      partO, partM, partL);

  // merge h0/h1 partials
  combine_kernel<<<dim3(128), dim3(256), 0, stream>>>(
      partO, partM, partL, if_gain, gate_buf, attn_buf);

  // final GEMM -> d_out (fp32)
  gemm_out<<<dim3(4, 128), dim3(256), 0, stream>>>(
      attn_buf, out_wt, out_b, out);

  (void)in_sizes; (void)n_in; (void)out_size; (void)ws_size;
}

// Round 7
// 136.097 us; speedup vs baseline: 1.0102x; 1.0102x over previous
//
#include <hip/hip_runtime.h>
#include <cmath>

typedef unsigned short u16;
typedef unsigned short u16x4 __attribute__((ext_vector_type(4)));
typedef unsigned short u16x8 __attribute__((ext_vector_type(8)));
typedef __bf16 bf16x8 __attribute__((ext_vector_type(8)));
typedef float f32x4 __attribute__((ext_vector_type(4)));

#define HNUM 8
#define HDIM 64
#define BATCH 4
#define NSEQ 2048
#define DMODEL 512
#define LP 72   // padded LDS row stride in u16 (144 B) for the attn kernel

__device__ __forceinline__ u16 f2bf(float f) {
  unsigned int u = __builtin_bit_cast(unsigned int, f);
  u += 0x7fffu + ((u >> 16) & 1u);          // round-to-nearest-even
  return (u16)(u >> 16);
}

__device__ __forceinline__ float bf2f(u16 v) {
  unsigned int u = ((unsigned int)v) << 16;
  return __builtin_bit_cast(float, u);
}

__device__ __forceinline__ f32x4 mfma_bf16(u16x8 a, u16x8 b, f32x4 c) {
  return __builtin_amdgcn_mfma_f32_16x16x32_bf16(
      __builtin_bit_cast(bf16x8, a), __builtin_bit_cast(bf16x8, b), c, 0, 0, 0);
}

// async global->LDS, 16 B per lane (dest must be wave-uniform base + lane*16)
__device__ __forceinline__ void gload16(u16* lds, const u16* g) {
  __builtin_amdgcn_global_load_lds(
      (const __attribute__((address_space(1))) void*)g,
      (__attribute__((address_space(3))) void*)lds, 16, 0, 0);
}

// stage a ROWS x 32 bf16 tile (row stride DMODEL) into linear LDS
template <int ROWS>
__device__ __forceinline__ void stage_tile(u16* lds, const u16* g, int tid) {
  #pragma unroll
  for (int i = 0; i < ROWS / 64; ++i) {
    const int off = (i * 256 + tid) * 8;
    const int row = off >> 5, col = off & 31;
    gload16(lds + off, g + (size_t)row * DMODEL + col);
  }
}

// ---------------------------------------------------------------------------
// Prep: fp32 -> bf16 convert (x), 8 elems/thread
// ---------------------------------------------------------------------------
__global__ __launch_bounds__(256) void cvt_bf16_kernel(
    const float* __restrict__ in, u16* __restrict__ out, int n8) {
  int i = blockIdx.x * 256 + threadIdx.x;
  if (i >= n8) return;
  const float4 f0 = *(const float4*)(in + i * 8);
  const float4 f1 = *(const float4*)(in + i * 8 + 4);
  u16x8 pk;
  pk[0] = f2bf(f0.x); pk[1] = f2bf(f0.y); pk[2] = f2bf(f0.z); pk[3] = f2bf(f0.w);
  pk[4] = f2bf(f1.x); pk[5] = f2bf(f1.y); pk[6] = f2bf(f1.z); pk[7] = f2bf(f1.w);
  *(u16x8*)(out + i * 8) = pk;
}

// ---------------------------------------------------------------------------
// Prep: W[K][N] fp32 -> Wt[N][K] bf16 (32x32 LDS tile transpose)
// ---------------------------------------------------------------------------
__global__ __launch_bounds__(256) void transpose_w_kernel(
    const float* __restrict__ W, u16* __restrict__ Wt, int K, int N) {
  __shared__ float tile[32][33];
  const int n0 = blockIdx.x * 32, k0 = blockIdx.y * 32;
  const int tx = threadIdx.x & 31, ty = threadIdx.x >> 5;
  #pragma unroll
  for (int yy = ty; yy < 32; yy += 8)
    tile[yy][tx] = W[(size_t)(k0 + yy) * N + n0 + tx];
  __syncthreads();
  #pragma unroll
  for (int yy = ty; yy < 32; yy += 8)
    Wt[(size_t)(n0 + yy) * K + k0 + tx] = f2bf(tile[tx][yy]);
}

// ---------------------------------------------------------------------------
// Prep: vbf[b,h,n,d] -> vbfT[b,h,d,n] (64x64 LDS tile transpose)
// ---------------------------------------------------------------------------
__global__ __launch_bounds__(256) void transpose_v_kernel(
    const u16* __restrict__ v, u16* __restrict__ vT) {
  __shared__ u16 t[64][LP];
  const int n0 = blockIdx.x * 64;
  const size_t bh = blockIdx.y;
  const int r = threadIdx.x >> 2, c0 = (threadIdx.x & 3) << 4;
  const u16* src = v + (bh * NSEQ + n0 + r) * HDIM + c0;
  u16x8 a0 = *(const u16x8*)src;
  u16x8 a1 = *(const u16x8*)(src + 8);
  #pragma unroll
  for (int j = 0; j < 8; ++j) {
    t[c0 + j][r] = a0[j];
    t[c0 + 8 + j][r] = a1[j];
  }
  __syncthreads();
  u16x8 o0 = *(const u16x8*)&t[r][c0];
  u16x8 o1 = *(const u16x8*)&t[r][c0 + 8];
  u16* dst = vT + (bh * HDIM + r) * NSEQ + n0 + c0;
  *(u16x8*)dst = o0;
  *(u16x8*)(dst + 8) = o1;
}

// ---------------------------------------------------------------------------
// Bias table: tab[h][d] = in_band(bucket(d),h) ? pos_bias[bucket(d)][h] : -100
// ---------------------------------------------------------------------------
__global__ __launch_bounds__(256) void bias_tab_kernel(
    const float* __restrict__ pos_bias, float* __restrict__ tab) {
  int d = blockIdx.x * 256 + threadIdx.x;   // 0..2047
  if (d >= NSEQ) return;
  int bkt;
  if (d < 28) {
    bkt = d;
  } else {
    double t = log((double)d / 28.0) / log(2048.0 / 28.0) * 16.0;
    int ti = 28 + (int)t;
    bkt = ti < 43 ? ti : 43;
  }
  const int lo[8] = {38, 34, 28, 20, 13, 7, 3, 0};
  const int hi[8] = {44, 40, 35, 28, 21, 14, 9, 6};
  #pragma unroll
  for (int h = 0; h < HNUM; ++h) {
    bool inb = (bkt >= lo[h]) && (bkt < hi[h]);
    tab[h * NSEQ + d] = inb ? pos_bias[bkt * HNUM + h] : -100.0f;
  }
}

// ---------------------------------------------------------------------------
// Fused qkv+gate GEMM: [8192,512]bf16 @ Wt[2048,512]^T, 128x128 tile, BK=32.
// 2-phase pipeline with STATIC double buffers (k-loop unrolled x2): per step
// STAGE(next) -> ds_read(cur) -> lgkmcnt(0)+sched_barrier -> 16 MFMA ->
// vmcnt(0) -> barrier. One barrier per k-step; loads drain under compute.
// ---------------------------------------------------------------------------
__global__ __launch_bounds__(256) void gemm_qkvg(
    const u16* __restrict__ Abf, const u16* __restrict__ Wt,
    const float* __restrict__ qkv_b, const float* __restrict__ gate_b,
    const float* __restrict__ kdelta, const float* __restrict__ vdelta,
    u16* __restrict__ qbf, u16* __restrict__ kbf, u16* __restrict__ vbf,
    u16* __restrict__ gate_buf) {
  __shared__ __align__(16) u16 As0[128 * 32];
  __shared__ __align__(16) u16 As1[128 * 32];
  __shared__ __align__(16) u16 Bs0[128 * 32];
  __shared__ __align__(16) u16 Bs1[128 * 32];

  const int m0 = blockIdx.y * 128, n0 = blockIdx.x * 128;
  const int tid = threadIdx.x;
  const int w = tid >> 6, l = tid & 63, li = l & 15, lg = l >> 4;
  const int wr = w >> 1, wc = w & 1;

  f32x4 acc[4][4];
  #pragma unroll
  for (int i = 0; i < 4; ++i)
    #pragma unroll
    for (int j = 0; j < 4; ++j) acc[i][j] = f32x4{0.f, 0.f, 0.f, 0.f};

  const u16* Ab = Abf + (size_t)m0 * DMODEL;
  const u16* Bb = Wt + (size_t)n0 * DMODEL;

  auto compute = [&](const u16* Asb, const u16* Bsb) {
    u16x8 af[4], bfr[4];
    #pragma unroll
    for (int mt = 0; mt < 4; ++mt)
      af[mt] = *(const u16x8*)&Asb[(wr * 64 + mt * 16 + li) * 32 + lg * 8];
    #pragma unroll
    for (int nt = 0; nt < 4; ++nt)
      bfr[nt] = *(const u16x8*)&Bsb[(wc * 64 + nt * 16 + li) * 32 + lg * 8];
    asm volatile("s_waitcnt lgkmcnt(0)" ::: "memory");
    __builtin_amdgcn_sched_barrier(0);
    #pragma unroll
    for (int mt = 0; mt < 4; ++mt)
      #pragma unroll
      for (int nt = 0; nt < 4; ++nt)
        acc[mt][nt] = mfma_bf16(af[mt], bfr[nt], acc[mt][nt]);
  };

  // prologue: stage step 0 into buffer 0
  stage_tile<128>(As0, Ab, tid);
  stage_tile<128>(Bs0, Bb, tid);
  asm volatile("s_waitcnt vmcnt(0)" ::: "memory");
  __syncthreads();

  #pragma unroll 1
  for (int kt2 = 0; kt2 < 8; ++kt2) {
    // phase A: compute step 2*kt2 from buf0; stage step 2*kt2+1 into buf1
    {
      const int kn = kt2 * 2 + 1;
      if (kn < 16) {
        stage_tile<128>(As1, Ab + kn * 32, tid);
        stage_tile<128>(Bs1, Bb + kn * 32, tid);
      }
      compute(As0, Bs0);
      asm volatile("s_waitcnt vmcnt(0)" ::: "memory");
      __syncthreads();
    }
    // phase B: compute step 2*kt2+1 from buf1; stage step 2*kt2+2 into buf0
    {
      const int kn = kt2 * 2 + 2;
      if (kn < 16) {
        stage_tile<128>(As0, Ab + kn * 32, tid);
        stage_tile<128>(Bs0, Bb + kn * 32, tid);
      }
      compute(As1, Bs1);
      asm volatile("s_waitcnt vmcnt(0)" ::: "memory");
      __syncthreads();
    }
  }

  // epilogue: row = m0+wr*64+mt*16+lg*4+r ; col = n0+wc*64+nt*16+li
  #pragma unroll
  for (int nt = 0; nt < 4; ++nt) {
    const int colg = n0 + wc * 64 + nt * 16 + li;
    const int which = colg >> 9;            // uniform per block (128 | 512)
    const int inner = colg & 511;
    const float bv = (which < 3) ? qkv_b[colg] : gate_b[inner];
    const int hh = inner >> 6, hd = inner & 63;
    #pragma unroll
    for (int mt = 0; mt < 4; ++mt) {
      const int rowbase = m0 + wr * 64 + mt * 16 + lg * 4;
      const int bb = rowbase >> 11, nn0 = rowbase & 2047;
      const size_t idx0 = (((size_t)bb * HNUM + hh) * NSEQ + nn0) * HDIM + hd;
      #pragma unroll
      for (int r = 0; r < 4; ++r) {
        const float val = acc[mt][nt][r] + bv;
        if (which == 0)
          qbf[idx0 + r * HDIM] = f2bf(val * 0.125f);       // fold 1/sqrt(HD)
        else if (which == 1)
          kbf[idx0 + r * HDIM] = f2bf(val + kdelta[idx0 + r * HDIM]);
        else if (which == 2)
          vbf[idx0 + r * HDIM] = f2bf(val + vdelta[idx0 + r * HDIM]);
        else
          gate_buf[(size_t)(rowbase + r) * DMODEL + inner] =
              f2bf(1.f / (1.f + __expf(-val)));
      }
    }
  }
}

// ---------------------------------------------------------------------------
// Out GEMM: [8192,512]bf16 @ out_wt[512,512]^T + out_b -> fp32. 64x128 tile,
// BK=32, same 2-phase static-dbuf pipeline. Grid (4,128) = 512 blocks.
// ---------------------------------------------------------------------------
__global__ __launch_bounds__(256) void gemm_out(
    const u16* __restrict__ Abf, const u16* __restrict__ Wt,
    const float* __restrict__ bias, float* __restrict__ outf) {
  __shared__ __align__(16) u16 As0[64 * 32];
  __shared__ __align__(16) u16 As1[64 * 32];
  __shared__ __align__(16) u16 Bs0[128 * 32];
  __shared__ __align__(16) u16 Bs1[128 * 32];

  const int m0 = blockIdx.y * 64, n0 = blockIdx.x * 128;
  const int tid = threadIdx.x;
  const int w = tid >> 6, l = tid & 63, li = l & 15, lg = l >> 4;
  const int wr = w >> 1, wc = w & 1;

  f32x4 acc[2][4];
  #pragma unroll
  for (int i = 0; i < 2; ++i)
    #pragma unroll
    for (int j = 0; j < 4; ++j) acc[i][j] = f32x4{0.f, 0.f, 0.f, 0.f};

  const u16* Ab = Abf + (size_t)m0 * DMODEL;
  const u16* Bb = Wt + (size_t)n0 * DMODEL;

  auto compute = [&](const u16* Asb, const u16* Bsb) {
    u16x8 af[2], bfr[4];
    #pragma unroll
    for (int mt = 0; mt < 2; ++mt)
      af[mt] = *(const u16x8*)&Asb[(wr * 32 + mt * 16 + li) * 32 + lg * 8];
    #pragma unroll
    for (int nt = 0; nt < 4; ++nt)
      bfr[nt] = *(const u16x8*)&Bsb[(wc * 64 + nt * 16 + li) * 32 + lg * 8];
    asm volatile("s_waitcnt lgkmcnt(0)" ::: "memory");
    __builtin_amdgcn_sched_barrier(0);
    #pragma unroll
    for (int mt = 0; mt < 2; ++mt)
      #pragma unroll
      for (int nt = 0; nt < 4; ++nt)
        acc[mt][nt] = mfma_bf16(af[mt], bfr[nt], acc[mt][nt]);
  };

  stage_tile<64>(As0, Ab, tid);
  stage_tile<128>(Bs0, Bb, tid);
  asm volatile("s_waitcnt vmcnt(0)" ::: "memory");
  __syncthreads();

  #pragma unroll 1
  for (int kt2 = 0; kt2 < 8; ++kt2) {
    {
      const int kn = kt2 * 2 + 1;
      if (kn < 16) {
        stage_tile<64>(As1, Ab + kn * 32, tid);
        stage_tile<128>(Bs1, Bb + kn * 32, tid);
      }
      compute(As0, Bs0);
      asm volatile("s_waitcnt vmcnt(0)" ::: "memory");
      __syncthreads();
    }
    {
      const int kn = kt2 * 2 + 2;
      if (kn < 16) {
        stage_tile<64>(As0, Ab + kn * 32, tid);
        stage_tile<128>(Bs0, Bb + kn * 32, tid);
      }
      compute(As1, Bs1);
      asm volatile("s_waitcnt vmcnt(0)" ::: "memory");
      __syncthreads();
    }
  }

  #pragma unroll
  for (int nt = 0; nt < 4; ++nt) {
    const int colg = n0 + wc * 64 + nt * 16 + li;
    const float bv = bias[colg];
    #pragma unroll
    for (int mt = 0; mt < 2; ++mt) {
      #pragma unroll
      for (int r = 0; r < 4; ++r) {
        const int rowg = m0 + wr * 32 + mt * 16 + lg * 4 + r;
        outf[(size_t)rowg * DMODEL + colg] = acc[mt][nt][r] + bv;
      }
    }
  }
}

// ---------------------------------------------------------------------------
// Flash attention, swapped-QK^T, banded KV windows, split-KV balanced chunks.
// (verified round-5/6 body, unchanged)
// ---------------------------------------------------------------------------
__global__ __launch_bounds__(256) void attn_kernel(
    const u16* __restrict__ qbf, const u16* __restrict__ kbf,
    const u16* __restrict__ vbfT, const float* __restrict__ bias_tab,
    const float* __restrict__ if_gain, const u16* __restrict__ gate,
    u16* __restrict__ attn_out, u16* __restrict__ partO,
    float* __restrict__ partM, float* __restrict__ partL) {
  __shared__ __align__(16) u16 Ks[64][LP];   // [kv][hd]
  __shared__ __align__(16) u16 Vt[64][LP];   // [hd][kv]
  __shared__ __align__(16) u16 Pl[4][16][LP];

  static const int DMINW[8] = {408, 139, 26, 18, 11, 5, 1, 0};
  static const int DMAXW[8] = {2049, 702, 185, 29, 22, 15, 10, 7};
  static const int DMINS[8] = {412, 143, 30, 22, 15, 9, 5, 2};
  static const int SH[12] = {0, 0, 0, 0, 1, 1, 2, 3, 4, 5, 6, 7};
  static const int SC[12] = {0, 1, 2, 3, 0, 1, 0, 0, 0, 0, 0, 0};
  static const int SN[12] = {4, 4, 4, 4, 2, 2, 1, 1, 1, 1, 1, 1};

  const int slot = blockIdx.x >> 7;
  const int rem = blockIdx.x & 127;
  const int qt = 31 - (rem >> 2);
  const int b = rem & 3;
  const int h = SH[slot], ch = SC[slot], nc = SN[slot];
  const int bh = b * HNUM + h;
  const int q0 = qt * 64;
  const int tid = threadIdx.x;
  const int w = tid >> 6, l = tid & 63, li = l & 15, lg = l >> 4;

  const u16* qrow = qbf + ((size_t)bh * NSEQ + q0 + w * 16 + li) * HDIM;
  u16x8 qf0 = *(const u16x8*)(qrow + lg * 8);
  u16x8 qf1 = *(const u16x8*)(qrow + 32 + lg * 8);

  const bool pure = q0 >= DMINS[h];
  int kv_lo = 0, kv_hi = q0 + 64;
  if (pure) {
    int lo = q0 - DMAXW[h];
    kv_lo = (lo > 0 ? lo : 0) & ~63;
    kv_hi = q0 + 64 - DMINW[h];
  }
  const int t0 = kv_lo >> 6, t1 = (kv_hi - 1) >> 6;
  const int len = t1 - t0 + 1;
  const int ta = t0 + (len * ch) / nc;
  const int tb = t0 + (len * (ch + 1)) / nc - 1;

  const int srow = tid >> 2;
  const int scb = (tid & 3) << 4;
  const float* btab = bias_tab + h * NSEQ;

  float mrun = -INFINITY, lrun = 0.f;
  f32x4 O[4] = {{0.f,0.f,0.f,0.f},{0.f,0.f,0.f,0.f},
                {0.f,0.f,0.f,0.f},{0.f,0.f,0.f,0.f}};

  for (int tt = ta; tt <= tb; ++tt) {
    const int kv0 = tt << 6;
    {
      const size_t kbase = ((size_t)bh * NSEQ + kv0 + srow) * HDIM + scb;
      u16x8 k0 = *(const u16x8*)(kbf + kbase);
      u16x8 k1 = *(const u16x8*)(kbf + kbase + 8);
      const size_t vbase = ((size_t)bh * HDIM + srow) * NSEQ + kv0 + scb;
      u16x8 v0 = *(const u16x8*)(vbfT + vbase);
      u16x8 v1 = *(const u16x8*)(vbfT + vbase + 8);
      *(u16x8*)&Ks[srow][scb] = k0;
      *(u16x8*)&Ks[srow][scb + 8] = k1;
      *(u16x8*)&Vt[srow][scb] = v0;
      *(u16x8*)&Vt[srow][scb + 8] = v1;
    }
    __syncthreads();

    f32x4 s[4];
    #pragma unroll
    for (int t = 0; t < 4; ++t) {
      u16x8 a0 = *(const u16x8*)&Ks[t * 16 + li][lg * 8];
      u16x8 a1 = *(const u16x8*)&Ks[t * 16 + li][32 + lg * 8];
      f32x4 acc = {0.f, 0.f, 0.f, 0.f};
      acc = mfma_bf16(a0, qf0, acc);
      acc = mfma_bf16(a1, qf1, acc);
      s[t] = acc;
    }

    const int D0 = (q0 + w * 16 + li) - kv0 - lg * 4;
    float rm = -1e30f;
    #pragma unroll
    for (int t = 0; t < 4; ++t) {
      #pragma unroll
      for (int r = 0; r < 4; ++r) {
        int d = D0 - 16 * t - r;
        float sv = s[t][r];
        sv = (d >= 0) ? (sv + btab[d]) : -1e30f;
        s[t][r] = sv;
        rm = fmaxf(rm, sv);
      }
    }
    rm = fmaxf(rm, __shfl_xor(rm, 16, 64));
    rm = fmaxf(rm, __shfl_xor(rm, 32, 64));
    const float mn = fmaxf(mrun, rm);
    const float f = __expf(mrun - mn);
    mrun = mn;
    float ps = 0.f;
    #pragma unroll
    for (int t = 0; t < 4; ++t) {
      #pragma unroll
      for (int r = 0; r < 4; ++r) {
        float p = __expf(s[t][r] - mn);
        s[t][r] = p;
        ps += p;
      }
    }
    ps += __shfl_xor(ps, 16, 64);
    ps += __shfl_xor(ps, 32, 64);
    lrun = lrun * f + ps;

    #pragma unroll
    for (int t = 0; t < 4; ++t) {
      u16x4 pk;
      pk[0] = f2bf(s[t][0]); pk[1] = f2bf(s[t][1]);
      pk[2] = f2bf(s[t][2]); pk[3] = f2bf(s[t][3]);
      *(u16x4*)&Pl[w][li][t * 16 + lg * 4] = pk;
    }

    float fr[4];
    #pragma unroll
    for (int r = 0; r < 4; ++r) fr[r] = __shfl(f, lg * 4 + r, 64);
    #pragma unroll
    for (int dt = 0; dt < 4; ++dt) {
      O[dt][0] *= fr[0]; O[dt][1] *= fr[1];
      O[dt][2] *= fr[2]; O[dt][3] *= fr[3];
    }
    __syncthreads();

    #pragma unroll
    for (int ks = 0; ks < 2; ++ks) {
      u16x8 pA = *(const u16x8*)&Pl[w][li][ks * 32 + lg * 8];
      #pragma unroll
      for (int dt = 0; dt < 4; ++dt) {
        u16x8 vB = *(const u16x8*)&Vt[dt * 16 + li][ks * 32 + lg * 8];
        O[dt] = mfma_bf16(pA, vB, O[dt]);
      }
    }
    __syncthreads();
  }

  if (nc == 1) {
    const float gain = if_gain[h];
    float linv[4];
    #pragma unroll
    for (int r = 0; r < 4; ++r)
      linv[r] = gain / __shfl(lrun, lg * 4 + r, 64);
    #pragma unroll
    for (int r = 0; r < 4; ++r) {
      const int i = q0 + w * 16 + lg * 4 + r;
      const size_t base = ((size_t)b * NSEQ + i) * DMODEL + h * HDIM + li;
      #pragma unroll
      for (int dt = 0; dt < 4; ++dt) {
        const float g = bf2f(gate[base + dt * 16]);
        attn_out[base + dt * 16] = f2bf(O[dt][r] * linv[r] * g);
      }
    }
  } else {
    const int sbase = (b * 32 + qt) * 6 + slot;   // slot in 0..5 here
    #pragma unroll
    for (int r = 0; r < 4; ++r) {
      const int rl = w * 16 + lg * 4 + r;
      #pragma unroll
      for (int dt = 0; dt < 4; ++dt)
        partO[(size_t)sbase * 4096 + rl * 64 + dt * 16 + li] = f2bf(O[dt][r]);
    }
    if (lg == 0) {
      partM[sbase * 64 + w * 16 + li] = mrun;
      partL[sbase * 64 + w * 16 + li] = lrun;
    }
  }
}

// ---------------------------------------------------------------------------
// Combine split-KV partials for h0 (4 chunks) and h1 (2 chunks).
// ---------------------------------------------------------------------------
__global__ __launch_bounds__(256) void combine_kernel(
    const u16* __restrict__ partO, const float* __restrict__ partM,
    const float* __restrict__ partL, const float* __restrict__ if_gain,
    const u16* __restrict__ gate, u16* __restrict__ attn_out) {
  const int b = blockIdx.x & 3, qt = blockIdx.x >> 2;
  const int tid = threadIdx.x;
  const int row = tid >> 2, d0 = (tid & 3) << 4;

  #pragma unroll
  for (int hc = 0; hc < 2; ++hc) {
    const int nc = hc ? 2 : 4, s0 = hc ? 4 : 0;
    const int sbase = (b * 32 + qt) * 6 + s0;
    float m[4], wch[4];
    float M = -INFINITY;
    #pragma unroll
    for (int c = 0; c < 4; ++c) {
      m[c] = (c < nc) ? partM[(sbase + c) * 64 + row] : -INFINITY;
      M = fmaxf(M, m[c]);
    }
    float den = 0.f;
    #pragma unroll
    for (int c = 0; c < 4; ++c) {
      wch[c] = (c < nc) ? __expf(m[c] - M) : 0.f;
      if (c < nc) den += wch[c] * partL[(sbase + c) * 64 + row];
    }
    float num[16];
    #pragma unroll
    for (int j = 0; j < 16; ++j) num[j] = 0.f;
    #pragma unroll
    for (int c = 0; c < 4; ++c) {
      if (c < nc) {
        const u16* op = partO + (size_t)(sbase + c) * 4096 + row * 64 + d0;
        u16x8 o0 = *(const u16x8*)op;
        u16x8 o1 = *(const u16x8*)(op + 8);
        #pragma unroll
        for (int j = 0; j < 8; ++j) {
          num[j]     += wch[c] * bf2f(o0[j]);
          num[8 + j] += wch[c] * bf2f(o1[j]);
        }
      }
    }
    const float inv = if_gain[hc] / den;
    const size_t obase =
        ((size_t)b * NSEQ + qt * 64 + row) * DMODEL + hc * HDIM + d0;
    u16x8 g0 = *(const u16x8*)(gate + obase);
    u16x8 g1 = *(const u16x8*)(gate + obase + 8);
    u16x8 r0, r1;
    #pragma unroll
    for (int j = 0; j < 8; ++j) {
      r0[j] = f2bf(num[j] * inv * bf2f(g0[j]));
      r1[j] = f2bf(num[8 + j] * inv * bf2f(g1[j]));
    }
    *(u16x8*)(attn_out + obase) = r0;
    *(u16x8*)(attn_out + obase + 8) = r1;
  }
}

// ---------------------------------------------------------------------------
extern "C" void kernel_launch(void* const* d_in, const int* in_sizes, int n_in,
                              void* d_out, int out_size, void* d_ws,
                              size_t ws_size, hipStream_t stream) {
  const float* x       = (const float*)d_in[0];
  const float* k_delta = (const float*)d_in[1];
  const float* v_delta = (const float*)d_in[2];
  const float* qkv_w   = (const float*)d_in[3];
  const float* qkv_b   = (const float*)d_in[4];
  const float* gate_w  = (const float*)d_in[5];
  const float* gate_b  = (const float*)d_in[6];
  const float* out_w   = (const float*)d_in[7];
  const float* out_b   = (const float*)d_in[8];
  const float* pos_bias = (const float*)d_in[9];
  const float* if_gain  = (const float*)d_in[10];
  float* out = (float*)d_out;
  char* ws = (char*)d_ws;

  // workspace layout (bytes)
  u16*   xbf      = (u16*)(ws + 0);              // 8,388,608 (dead after gemm)
  u16*   qbf      = (u16*)(ws + 8388608);        // 8,388,608
  u16*   kbf      = (u16*)(ws + 16777216);       // 8,388,608
  u16*   vbf      = (u16*)(ws + 25165824);       // 8,388,608 (dead after v-T)
  u16*   vbfT     = (u16*)(ws + 33554432);       // 8,388,608
  u16*   gate_buf = (u16*)(ws + 41943040);       // 8,388,608
  u16*   fused_wt = (u16*)(ws + 50331648);       // 2,097,152
  u16*   out_wt   = (u16*)(ws + 52428800);       //   524,288
  float* bias_tab = (float*)(ws + 52953088);     //    65,536
  // aliases (stream-ordered safe):
  u16*   attn_buf = vbf;                         // vbf dead after transpose_v
  u16*   partO = (u16*)(ws + 0);                 // xbf dead after gemm_qkvg
  float* partM = (float*)(ws + 6291456);
  float* partL = (float*)(ws + 6488064);

  // prep
  cvt_bf16_kernel<<<dim3(2048), dim3(256), 0, stream>>>(
      x, xbf, BATCH * NSEQ * DMODEL / 8);
  transpose_w_kernel<<<dim3(48, 16), dim3(256), 0, stream>>>(
      qkv_w, fused_wt, DMODEL, 3 * DMODEL);
  transpose_w_kernel<<<dim3(16, 16), dim3(256), 0, stream>>>(
      gate_w, fused_wt + (size_t)3 * DMODEL * DMODEL, DMODEL, DMODEL);
  transpose_w_kernel<<<dim3(16, 16), dim3(256), 0, stream>>>(
      out_w, out_wt, DMODEL, DMODEL);
  bias_tab_kernel<<<dim3(8), dim3(256), 0, stream>>>(pos_bias, bias_tab);

  // fused qkv+gate GEMM (v row-major)
  gemm_qkvg<<<dim3(16, 64), dim3(256), 0, stream>>>(
      xbf, fused_wt, qkv_b, gate_b, k_delta, v_delta,
      qbf, kbf, vbf, gate_buf);

  // v -> v^T
  transpose_v_kernel<<<dim3(32, 32), dim3(256), 0, stream>>>(vbf, vbfT);

  // flash attention: split-KV balanced chunks
  attn_kernel<<<dim3(1536), dim3(256), 0, stream>>>(
      qbf, kbf, vbfT, bias_tab, if_gain, gate_buf, attn_buf,
      partO, partM, partL);

  // merge h0/h1 partials
  combine_kernel<<<dim3(128), dim3(256), 0, stream>>>(
      partO, partM, partL, if_gain, gate_buf, attn_buf);

  // final GEMM -> d_out (fp32)
  gemm_out<<<dim3(4, 128), dim3(256), 0, stream>>>(
      attn_buf, out_wt, out_b, out);

  (void)in_sizes; (void)n_in; (void)out_size; (void)ws_size;
}

// Round 8
// 114.950 us; speedup vs baseline: 1.1960x; 1.1840x over previous
//
#include <hip/hip_runtime.h>
#include <cmath>

typedef unsigned short u16;
typedef unsigned short u16x4 __attribute__((ext_vector_type(4)));
typedef unsigned short u16x8 __attribute__((ext_vector_type(8)));
typedef __bf16 bf16x8 __attribute__((ext_vector_type(8)));
typedef float f32x4 __attribute__((ext_vector_type(4)));

#define HNUM 8
#define HDIM 64
#define BATCH 4
#define NSEQ 2048
#define DMODEL 512
#define NFUSED 2048
#define LP 72   // padded LDS row stride in u16 (144 B) for the attn kernel

__device__ __forceinline__ u16 f2bf(float f) {
  unsigned int u = __builtin_bit_cast(unsigned int, f);
  u += 0x7fffu + ((u >> 16) & 1u);          // round-to-nearest-even
  return (u16)(u >> 16);
}

__device__ __forceinline__ float bf2f(u16 v) {
  unsigned int u = ((unsigned int)v) << 16;
  return __builtin_bit_cast(float, u);
}

__device__ __forceinline__ f32x4 mfma_bf16(u16x8 a, u16x8 b, f32x4 c) {
  return __builtin_amdgcn_mfma_f32_16x16x32_bf16(
      __builtin_bit_cast(bf16x8, a), __builtin_bit_cast(bf16x8, b), c, 0, 0, 0);
}

// async global->LDS, 16 B per lane (dest must be wave-uniform base + lane*16)
__device__ __forceinline__ void gload16(u16* lds, const u16* g) {
  __builtin_amdgcn_global_load_lds(
      (const __attribute__((address_space(1))) void*)g,
      (__attribute__((address_space(3))) void*)lds, 16, 0, 0);
}

// stage a ROWS x 32 bf16 tile (row stride DMODEL) into linear LDS
template <int ROWS>
__device__ __forceinline__ void stage_tile(u16* lds, const u16* g, int tid) {
  #pragma unroll
  for (int i = 0; i < ROWS / 64; ++i) {
    const int off = (i * 256 + tid) * 8;
    const int row = off >> 5, col = off & 31;
    gload16(lds + off, g + (size_t)row * DMODEL + col);
  }
}

// ---------------------------------------------------------------------------
// Prep: fp32 -> bf16 convert (x), 8 elems/thread
// ---------------------------------------------------------------------------
__global__ __launch_bounds__(256) void cvt_bf16_kernel(
    const float* __restrict__ in, u16* __restrict__ out, int n8) {
  int i = blockIdx.x * 256 + threadIdx.x;
  if (i >= n8) return;
  const float4 f0 = *(const float4*)(in + i * 8);
  const float4 f1 = *(const float4*)(in + i * 8 + 4);
  u16x8 pk;
  pk[0] = f2bf(f0.x); pk[1] = f2bf(f0.y); pk[2] = f2bf(f0.z); pk[3] = f2bf(f0.w);
  pk[4] = f2bf(f1.x); pk[5] = f2bf(f1.y); pk[6] = f2bf(f1.z); pk[7] = f2bf(f1.w);
  *(u16x8*)(out + i * 8) = pk;
}

// ---------------------------------------------------------------------------
// Prep: W[K][N] fp32 -> Wt[N][K] bf16 (32x32 LDS tile transpose)
// ---------------------------------------------------------------------------
__global__ __launch_bounds__(256) void transpose_w_kernel(
    const float* __restrict__ W, u16* __restrict__ Wt, int K, int N) {
  __shared__ float tile[32][33];
  const int n0 = blockIdx.x * 32, k0 = blockIdx.y * 32;
  const int tx = threadIdx.x & 31, ty = threadIdx.x >> 5;
  #pragma unroll
  for (int yy = ty; yy < 32; yy += 8)
    tile[yy][tx] = W[(size_t)(k0 + yy) * N + n0 + tx];
  __syncthreads();
  #pragma unroll
  for (int yy = ty; yy < 32; yy += 8)
    Wt[(size_t)(n0 + yy) * K + k0 + tx] = f2bf(tile[tx][yy]);
}

// ---------------------------------------------------------------------------
// Prep: vbf[b,h,n,d] -> vbfT[b,h,d,n] (64x64 LDS tile transpose)
// ---------------------------------------------------------------------------
__global__ __launch_bounds__(256) void transpose_v_kernel(
    const u16* __restrict__ v, u16* __restrict__ vT) {
  __shared__ u16 t[64][LP];
  const int n0 = blockIdx.x * 64;
  const size_t bh = blockIdx.y;
  const int r = threadIdx.x >> 2, c0 = (threadIdx.x & 3) << 4;
  const u16* src = v + (bh * NSEQ + n0 + r) * HDIM + c0;
  u16x8 a0 = *(const u16x8*)src;
  u16x8 a1 = *(const u16x8*)(src + 8);
  #pragma unroll
  for (int j = 0; j < 8; ++j) {
    t[c0 + j][r] = a0[j];
    t[c0 + 8 + j][r] = a1[j];
  }
  __syncthreads();
  u16x8 o0 = *(const u16x8*)&t[r][c0];
  u16x8 o1 = *(const u16x8*)&t[r][c0 + 8];
  u16* dst = vT + (bh * HDIM + r) * NSEQ + n0 + c0;
  *(u16x8*)dst = o0;
  *(u16x8*)(dst + 8) = o1;
}

// ---------------------------------------------------------------------------
// Bias table: tab[h][d] = in_band(bucket(d),h) ? pos_bias[bucket(d)][h] : -100
// ---------------------------------------------------------------------------
__global__ __launch_bounds__(256) void bias_tab_kernel(
    const float* __restrict__ pos_bias, float* __restrict__ tab) {
  int d = blockIdx.x * 256 + threadIdx.x;   // 0..2047
  if (d >= NSEQ) return;
  int bkt;
  if (d < 28) {
    bkt = d;
  } else {
    double t = log((double)d / 28.0) / log(2048.0 / 28.0) * 16.0;
    int ti = 28 + (int)t;
    bkt = ti < 43 ? ti : 43;
  }
  const int lo[8] = {38, 34, 28, 20, 13, 7, 3, 0};
  const int hi[8] = {44, 40, 35, 28, 21, 14, 9, 6};
  #pragma unroll
  for (int h = 0; h < HNUM; ++h) {
    bool inb = (bkt >= lo[h]) && (bkt < hi[h]);
    tab[h * NSEQ + d] = inb ? pos_bias[bkt * HNUM + h] : -100.0f;
  }
}

// ---------------------------------------------------------------------------
// Fused qkv+gate GEMM -> C[8192,2048] bf16 (bias added, NO scatter).
// 128x128 tile, BK=32, 2-phase static dbuf, XCD-swizzled block mapping
// (each XCD owns an 8-M-tile band: 1MB A + 2MB W fit its 4MB L2).
// Epilogue: acc -> LDS C-tile (reuses staging LDS) -> coalesced u16x8 stores.
// ---------------------------------------------------------------------------
__global__ __launch_bounds__(256) void gemm_fused(
    const u16* __restrict__ Abf, const u16* __restrict__ Wt,
    const float* __restrict__ qkv_b, const float* __restrict__ gate_b,
    u16* __restrict__ C) {
  __shared__ __align__(16) u16 S[4][128 * 32];
  u16* As0 = S[0]; u16* As1 = S[1]; u16* Bs0 = S[2]; u16* Bs1 = S[3];

  // XCD swizzle: linear id -> (xcd chunk of 128) -> m-major within chunk
  const int bid = blockIdx.y * 16 + blockIdx.x;   // HW dispatch order
  const int nb = (bid & 7) * 128 + (bid >> 3);
  const int m0 = (nb >> 4) * 128;
  const int n0 = (nb & 15) * 128;

  const int tid = threadIdx.x;
  const int w = tid >> 6, l = tid & 63, li = l & 15, lg = l >> 4;
  const int wr = w >> 1, wc = w & 1;

  f32x4 acc[4][4];
  #pragma unroll
  for (int i = 0; i < 4; ++i)
    #pragma unroll
    for (int j = 0; j < 4; ++j) acc[i][j] = f32x4{0.f, 0.f, 0.f, 0.f};

  const u16* Ab = Abf + (size_t)m0 * DMODEL;
  const u16* Bb = Wt + (size_t)n0 * DMODEL;

  auto compute = [&](const u16* Asb, const u16* Bsb) {
    u16x8 af[4], bfr[4];
    #pragma unroll
    for (int mt = 0; mt < 4; ++mt)
      af[mt] = *(const u16x8*)&Asb[(wr * 64 + mt * 16 + li) * 32 + lg * 8];
    #pragma unroll
    for (int nt = 0; nt < 4; ++nt)
      bfr[nt] = *(const u16x8*)&Bsb[(wc * 64 + nt * 16 + li) * 32 + lg * 8];
    asm volatile("s_waitcnt lgkmcnt(0)" ::: "memory");
    __builtin_amdgcn_sched_barrier(0);
    #pragma unroll
    for (int mt = 0; mt < 4; ++mt)
      #pragma unroll
      for (int nt = 0; nt < 4; ++nt)
        acc[mt][nt] = mfma_bf16(af[mt], bfr[nt], acc[mt][nt]);
  };

  stage_tile<128>(As0, Ab, tid);
  stage_tile<128>(Bs0, Bb, tid);
  asm volatile("s_waitcnt vmcnt(0)" ::: "memory");
  __syncthreads();

  #pragma unroll 1
  for (int kt2 = 0; kt2 < 8; ++kt2) {
    {
      const int kn = kt2 * 2 + 1;
      if (kn < 16) {
        stage_tile<128>(As1, Ab + kn * 32, tid);
        stage_tile<128>(Bs1, Bb + kn * 32, tid);
      }
      compute(As0, Bs0);
      asm volatile("s_waitcnt vmcnt(0)" ::: "memory");
      __syncthreads();
    }
    {
      const int kn = kt2 * 2 + 2;
      if (kn < 16) {
        stage_tile<128>(As0, Ab + kn * 32, tid);
        stage_tile<128>(Bs0, Bb + kn * 32, tid);
      }
      compute(As1, Bs1);
      asm volatile("s_waitcnt vmcnt(0)" ::: "memory");
      __syncthreads();
    }
  }

  // ---- epilogue: acc + bias -> LDS 128x128 tile -> coalesced stores ----
  u16* Ct = S[0];                       // 32 KB, staging done
  #pragma unroll
  for (int nt = 0; nt < 4; ++nt) {
    const int colg = n0 + wc * 64 + nt * 16 + li;
    const float bv = (colg < 3 * DMODEL) ? qkv_b[colg] : gate_b[colg & 511];
    const int col = wc * 64 + nt * 16 + li;
    #pragma unroll
    for (int mt = 0; mt < 4; ++mt) {
      const int row = wr * 64 + mt * 16 + lg * 4;
      #pragma unroll
      for (int r = 0; r < 4; ++r)
        Ct[(row + r) * 128 + col] = f2bf(acc[mt][nt][r] + bv);
    }
  }
  __syncthreads();
  #pragma unroll
  for (int p = 0; p < 8; ++p) {
    const int row = p * 16 + (tid >> 4);
    const int cc = (tid & 15) * 8;
    *(u16x8*)&C[(size_t)(m0 + row) * NFUSED + n0 + cc] =
        *(const u16x8*)&Ct[row * 128 + cc];
  }
}

// ---------------------------------------------------------------------------
// Pack: C[8192,2048] -> qbf (x0.125) | kbf (+kdelta) | vbf (+vdelta) |
//       gate (sigmoid).  Fully coalesced streaming; block = one row.
// ---------------------------------------------------------------------------
__global__ __launch_bounds__(256) void pack_kernel(
    const u16* __restrict__ C, const float* __restrict__ kdelta,
    const float* __restrict__ vdelta, u16* __restrict__ qbf,
    u16* __restrict__ kbf, u16* __restrict__ vbf, u16* __restrict__ gate) {
  const int rg = blockIdx.x;            // 0..8191
  const int b = rg >> 11, n = rg & 2047;
  const int col = threadIdx.x * 8;      // 0..2040
  const int seg = col >> 9;             // 0=q 1=k 2=v 3=gate
  const int inner = col & 511;
  const int h = inner >> 6, hd = inner & 63;

  u16x8 cv = *(const u16x8*)&C[(size_t)rg * NFUSED + col];
  const size_t hidx = (((size_t)b * HNUM + h) * NSEQ + n) * HDIM + hd;

  if (seg == 0) {
    u16x8 o;
    #pragma unroll
    for (int j = 0; j < 8; ++j) o[j] = f2bf(bf2f(cv[j]) * 0.125f);
    *(u16x8*)&qbf[hidx] = o;
  } else if (seg == 1) {
    float4 d0 = *(const float4*)&kdelta[hidx];
    float4 d1 = *(const float4*)&kdelta[hidx + 4];
    u16x8 o;
    o[0] = f2bf(bf2f(cv[0]) + d0.x); o[1] = f2bf(bf2f(cv[1]) + d0.y);
    o[2] = f2bf(bf2f(cv[2]) + d0.z); o[3] = f2bf(bf2f(cv[3]) + d0.w);
    o[4] = f2bf(bf2f(cv[4]) + d1.x); o[5] = f2bf(bf2f(cv[5]) + d1.y);
    o[6] = f2bf(bf2f(cv[6]) + d1.z); o[7] = f2bf(bf2f(cv[7]) + d1.w);
    *(u16x8*)&kbf[hidx] = o;
  } else if (seg == 2) {
    float4 d0 = *(const float4*)&vdelta[hidx];
    float4 d1 = *(const float4*)&vdelta[hidx + 4];
    u16x8 o;
    o[0] = f2bf(bf2f(cv[0]) + d0.x); o[1] = f2bf(bf2f(cv[1]) + d0.y);
    o[2] = f2bf(bf2f(cv[2]) + d0.z); o[3] = f2bf(bf2f(cv[3]) + d0.w);
    o[4] = f2bf(bf2f(cv[4]) + d1.x); o[5] = f2bf(bf2f(cv[5]) + d1.y);
    o[6] = f2bf(bf2f(cv[6]) + d1.z); o[7] = f2bf(bf2f(cv[7]) + d1.w);
    *(u16x8*)&vbf[hidx] = o;
  } else {
    u16x8 o;
    #pragma unroll
    for (int j = 0; j < 8; ++j)
      o[j] = f2bf(1.f / (1.f + __expf(-bf2f(cv[j]))));
    *(u16x8*)&gate[(size_t)rg * DMODEL + inner] = o;
  }
}

// ---------------------------------------------------------------------------
// Out GEMM: [8192,512]bf16 @ out_wt[512,512]^T + out_b -> fp32. 64x128 tile,
// BK=32, 2-phase static-dbuf pipeline. Grid (4,128) = 512 blocks.
// ---------------------------------------------------------------------------
__global__ __launch_bounds__(256) void gemm_out(
    const u16* __restrict__ Abf, const u16* __restrict__ Wt,
    const float* __restrict__ bias, float* __restrict__ outf) {
  __shared__ __align__(16) u16 As0[64 * 32];
  __shared__ __align__(16) u16 As1[64 * 32];
  __shared__ __align__(16) u16 Bs0[128 * 32];
  __shared__ __align__(16) u16 Bs1[128 * 32];

  const int m0 = blockIdx.y * 64, n0 = blockIdx.x * 128;
  const int tid = threadIdx.x;
  const int w = tid >> 6, l = tid & 63, li = l & 15, lg = l >> 4;
  const int wr = w >> 1, wc = w & 1;

  f32x4 acc[2][4];
  #pragma unroll
  for (int i = 0; i < 2; ++i)
    #pragma unroll
    for (int j = 0; j < 4; ++j) acc[i][j] = f32x4{0.f, 0.f, 0.f, 0.f};

  const u16* Ab = Abf + (size_t)m0 * DMODEL;
  const u16* Bb = Wt + (size_t)n0 * DMODEL;

  auto compute = [&](const u16* Asb, const u16* Bsb) {
    u16x8 af[2], bfr[4];
    #pragma unroll
    for (int mt = 0; mt < 2; ++mt)
      af[mt] = *(const u16x8*)&Asb[(wr * 32 + mt * 16 + li) * 32 + lg * 8];
    #pragma unroll
    for (int nt = 0; nt < 4; ++nt)
      bfr[nt] = *(const u16x8*)&Bsb[(wc * 64 + nt * 16 + li) * 32 + lg * 8];
    asm volatile("s_waitcnt lgkmcnt(0)" ::: "memory");
    __builtin_amdgcn_sched_barrier(0);
    #pragma unroll
    for (int mt = 0; mt < 2; ++mt)
      #pragma unroll
      for (int nt = 0; nt < 4; ++nt)
        acc[mt][nt] = mfma_bf16(af[mt], bfr[nt], acc[mt][nt]);
  };

  stage_tile<64>(As0, Ab, tid);
  stage_tile<128>(Bs0, Bb, tid);
  asm volatile("s_waitcnt vmcnt(0)" ::: "memory");
  __syncthreads();

  #pragma unroll 1
  for (int kt2 = 0; kt2 < 8; ++kt2) {
    {
      const int kn = kt2 * 2 + 1;
      if (kn < 16) {
        stage_tile<64>(As1, Ab + kn * 32, tid);
        stage_tile<128>(Bs1, Bb + kn * 32, tid);
      }
      compute(As0, Bs0);
      asm volatile("s_waitcnt vmcnt(0)" ::: "memory");
      __syncthreads();
    }
    {
      const int kn = kt2 * 2 + 2;
      if (kn < 16) {
        stage_tile<64>(As0, Ab + kn * 32, tid);
        stage_tile<128>(Bs0, Bb + kn * 32, tid);
      }
      compute(As1, Bs1);
      asm volatile("s_waitcnt vmcnt(0)" ::: "memory");
      __syncthreads();
    }
  }

  #pragma unroll
  for (int nt = 0; nt < 4; ++nt) {
    const int colg = n0 + wc * 64 + nt * 16 + li;
    const float bv = bias[colg];
    #pragma unroll
    for (int mt = 0; mt < 2; ++mt) {
      #pragma unroll
      for (int r = 0; r < 4; ++r) {
        const int rowg = m0 + wr * 32 + mt * 16 + lg * 4 + r;
        outf[(size_t)rowg * DMODEL + colg] = acc[mt][nt][r] + bv;
      }
    }
  }
}

// ---------------------------------------------------------------------------
// Flash attention, swapped-QK^T, banded KV windows, split-KV balanced chunks.
// (verified round-5/6/7 body, unchanged)
// ---------------------------------------------------------------------------
__global__ __launch_bounds__(256) void attn_kernel(
    const u16* __restrict__ qbf, const u16* __restrict__ kbf,
    const u16* __restrict__ vbfT, const float* __restrict__ bias_tab,
    const float* __restrict__ if_gain, const u16* __restrict__ gate,
    u16* __restrict__ attn_out, u16* __restrict__ partO,
    float* __restrict__ partM, float* __restrict__ partL) {
  __shared__ __align__(16) u16 Ks[64][LP];   // [kv][hd]
  __shared__ __align__(16) u16 Vt[64][LP];   // [hd][kv]
  __shared__ __align__(16) u16 Pl[4][16][LP];

  static const int DMINW[8] = {408, 139, 26, 18, 11, 5, 1, 0};
  static const int DMAXW[8] = {2049, 702, 185, 29, 22, 15, 10, 7};
  static const int DMINS[8] = {412, 143, 30, 22, 15, 9, 5, 2};
  static const int SH[12] = {0, 0, 0, 0, 1, 1, 2, 3, 4, 5, 6, 7};
  static const int SC[12] = {0, 1, 2, 3, 0, 1, 0, 0, 0, 0, 0, 0};
  static const int SN[12] = {4, 4, 4, 4, 2, 2, 1, 1, 1, 1, 1, 1};

  const int slot = blockIdx.x >> 7;
  const int rem = blockIdx.x & 127;
  const int qt = 31 - (rem >> 2);
  const int b = rem & 3;
  const int h = SH[slot], ch = SC[slot], nc = SN[slot];
  const int bh = b * HNUM + h;
  const int q0 = qt * 64;
  const int tid = threadIdx.x;
  const int w = tid >> 6, l = tid & 63, li = l & 15, lg = l >> 4;

  const u16* qrow = qbf + ((size_t)bh * NSEQ + q0 + w * 16 + li) * HDIM;
  u16x8 qf0 = *(const u16x8*)(qrow + lg * 8);
  u16x8 qf1 = *(const u16x8*)(qrow + 32 + lg * 8);

  const bool pure = q0 >= DMINS[h];
  int kv_lo = 0, kv_hi = q0 + 64;
  if (pure) {
    int lo = q0 - DMAXW[h];
    kv_lo = (lo > 0 ? lo : 0) & ~63;
    kv_hi = q0 + 64 - DMINW[h];
  }
  const int t0 = kv_lo >> 6, t1 = (kv_hi - 1) >> 6;
  const int len = t1 - t0 + 1;
  const int ta = t0 + (len * ch) / nc;
  const int tb = t0 + (len * (ch + 1)) / nc - 1;

  const int srow = tid >> 2;
  const int scb = (tid & 3) << 4;
  const float* btab = bias_tab + h * NSEQ;

  float mrun = -INFINITY, lrun = 0.f;
  f32x4 O[4] = {{0.f,0.f,0.f,0.f},{0.f,0.f,0.f,0.f},
                {0.f,0.f,0.f,0.f},{0.f,0.f,0.f,0.f}};

  for (int tt = ta; tt <= tb; ++tt) {
    const int kv0 = tt << 6;
    {
      const size_t kbase = ((size_t)bh * NSEQ + kv0 + srow) * HDIM + scb;
      u16x8 k0 = *(const u16x8*)(kbf + kbase);
      u16x8 k1 = *(const u16x8*)(kbf + kbase + 8);
      const size_t vbase = ((size_t)bh * HDIM + srow) * NSEQ + kv0 + scb;
      u16x8 v0 = *(const u16x8*)(vbfT + vbase);
      u16x8 v1 = *(const u16x8*)(vbfT + vbase + 8);
      *(u16x8*)&Ks[srow][scb] = k0;
      *(u16x8*)&Ks[srow][scb + 8] = k1;
      *(u16x8*)&Vt[srow][scb] = v0;
      *(u16x8*)&Vt[srow][scb + 8] = v1;
    }
    __syncthreads();

    f32x4 s[4];
    #pragma unroll
    for (int t = 0; t < 4; ++t) {
      u16x8 a0 = *(const u16x8*)&Ks[t * 16 + li][lg * 8];
      u16x8 a1 = *(const u16x8*)&Ks[t * 16 + li][32 + lg * 8];
      f32x4 acc = {0.f, 0.f, 0.f, 0.f};
      acc = mfma_bf16(a0, qf0, acc);
      acc = mfma_bf16(a1, qf1, acc);
      s[t] = acc;
    }

    const int D0 = (q0 + w * 16 + li) - kv0 - lg * 4;
    float rm = -1e30f;
    #pragma unroll
    for (int t = 0; t < 4; ++t) {
      #pragma unroll
      for (int r = 0; r < 4; ++r) {
        int d = D0 - 16 * t - r;
        float sv = s[t][r];
        sv = (d >= 0) ? (sv + btab[d]) : -1e30f;
        s[t][r] = sv;
        rm = fmaxf(rm, sv);
      }
    }
    rm = fmaxf(rm, __shfl_xor(rm, 16, 64));
    rm = fmaxf(rm, __shfl_xor(rm, 32, 64));
    const float mn = fmaxf(mrun, rm);
    const float f = __expf(mrun - mn);
    mrun = mn;
    float ps = 0.f;
    #pragma unroll
    for (int t = 0; t < 4; ++t) {
      #pragma unroll
      for (int r = 0; r < 4; ++r) {
        float p = __expf(s[t][r] - mn);
        s[t][r] = p;
        ps += p;
      }
    }
    ps += __shfl_xor(ps, 16, 64);
    ps += __shfl_xor(ps, 32, 64);
    lrun = lrun * f + ps;

    #pragma unroll
    for (int t = 0; t < 4; ++t) {
      u16x4 pk;
      pk[0] = f2bf(s[t][0]); pk[1] = f2bf(s[t][1]);
      pk[2] = f2bf(s[t][2]); pk[3] = f2bf(s[t][3]);
      *(u16x4*)&Pl[w][li][t * 16 + lg * 4] = pk;
    }

    float fr[4];
    #pragma unroll
    for (int r = 0; r < 4; ++r) fr[r] = __shfl(f, lg * 4 + r, 64);
    #pragma unroll
    for (int dt = 0; dt < 4; ++dt) {
      O[dt][0] *= fr[0]; O[dt][1] *= fr[1];
      O[dt][2] *= fr[2]; O[dt][3] *= fr[3];
    }
    __syncthreads();

    #pragma unroll
    for (int ks = 0; ks < 2; ++ks) {
      u16x8 pA = *(const u16x8*)&Pl[w][li][ks * 32 + lg * 8];
      #pragma unroll
      for (int dt = 0; dt < 4; ++dt) {
        u16x8 vB = *(const u16x8*)&Vt[dt * 16 + li][ks * 32 + lg * 8];
        O[dt] = mfma_bf16(pA, vB, O[dt]);
      }
    }
    __syncthreads();
  }

  if (nc == 1) {
    const float gain = if_gain[h];
    float linv[4];
    #pragma unroll
    for (int r = 0; r < 4; ++r)
      linv[r] = gain / __shfl(lrun, lg * 4 + r, 64);
    #pragma unroll
    for (int r = 0; r < 4; ++r) {
      const int i = q0 + w * 16 + lg * 4 + r;
      const size_t base = ((size_t)b * NSEQ + i) * DMODEL + h * HDIM + li;
      #pragma unroll
      for (int dt = 0; dt < 4; ++dt) {
        const float g = bf2f(gate[base + dt * 16]);
        attn_out[base + dt * 16] = f2bf(O[dt][r] * linv[r] * g);
      }
    }
  } else {
    const int sbase = (b * 32 + qt) * 6 + slot;   // slot in 0..5 here
    #pragma unroll
    for (int r = 0; r < 4; ++r) {
      const int rl = w * 16 + lg * 4 + r;
      #pragma unroll
      for (int dt = 0; dt < 4; ++dt)
        partO[(size_t)sbase * 4096 + rl * 64 + dt * 16 + li] = f2bf(O[dt][r]);
    }
    if (lg == 0) {
      partM[sbase * 64 + w * 16 + li] = mrun;
      partL[sbase * 64 + w * 16 + li] = lrun;
    }
  }
}

// ---------------------------------------------------------------------------
// Combine split-KV partials for h0 (4 chunks) and h1 (2 chunks).
// ---------------------------------------------------------------------------
__global__ __launch_bounds__(256) void combine_kernel(
    const u16* __restrict__ partO, const float* __restrict__ partM,
    const float* __restrict__ partL, const float* __restrict__ if_gain,
    const u16* __restrict__ gate, u16* __restrict__ attn_out) {
  const int b = blockIdx.x & 3, qt = blockIdx.x >> 2;
  const int tid = threadIdx.x;
  const int row = tid >> 2, d0 = (tid & 3) << 4;

  #pragma unroll
  for (int hc = 0; hc < 2; ++hc) {
    const int nc = hc ? 2 : 4, s0 = hc ? 4 : 0;
    const int sbase = (b * 32 + qt) * 6 + s0;
    float m[4], wch[4];
    float M = -INFINITY;
    #pragma unroll
    for (int c = 0; c < 4; ++c) {
      m[c] = (c < nc) ? partM[(sbase + c) * 64 + row] : -INFINITY;
      M = fmaxf(M, m[c]);
    }
    float den = 0.f;
    #pragma unroll
    for (int c = 0; c < 4; ++c) {
      wch[c] = (c < nc) ? __expf(m[c] - M) : 0.f;
      if (c < nc) den += wch[c] * partL[(sbase + c) * 64 + row];
    }
    float num[16];
    #pragma unroll
    for (int j = 0; j < 16; ++j) num[j] = 0.f;
    #pragma unroll
    for (int c = 0; c < 4; ++c) {
      if (c < nc) {
        const u16* op = partO + (size_t)(sbase + c) * 4096 + row * 64 + d0;
        u16x8 o0 = *(const u16x8*)op;
        u16x8 o1 = *(const u16x8*)(op + 8);
        #pragma unroll
        for (int j = 0; j < 8; ++j) {
          num[j]     += wch[c] * bf2f(o0[j]);
          num[8 + j] += wch[c] * bf2f(o1[j]);
        }
      }
    }
    const float inv = if_gain[hc] / den;
    const size_t obase =
        ((size_t)b * NSEQ + qt * 64 + row) * DMODEL + hc * HDIM + d0;
    u16x8 g0 = *(const u16x8*)(gate + obase);
    u16x8 g1 = *(const u16x8*)(gate + obase + 8);
    u16x8 r0, r1;
    #pragma unroll
    for (int j = 0; j < 8; ++j) {
      r0[j] = f2bf(num[j] * inv * bf2f(g0[j]));
      r1[j] = f2bf(num[8 + j] * inv * bf2f(g1[j]));
    }
    *(u16x8*)(attn_out + obase) = r0;
    *(u16x8*)(attn_out + obase + 8) = r1;
  }
}

// ---------------------------------------------------------------------------
extern "C" void kernel_launch(void* const* d_in, const int* in_sizes, int n_in,
                              void* d_out, int out_size, void* d_ws,
                              size_t ws_size, hipStream_t stream) {
  const float* x       = (const float*)d_in[0];
  const float* k_delta = (const float*)d_in[1];
  const float* v_delta = (const float*)d_in[2];
  const float* qkv_w   = (const float*)d_in[3];
  const float* qkv_b   = (const float*)d_in[4];
  const float* gate_w  = (const float*)d_in[5];
  const float* gate_b  = (const float*)d_in[6];
  const float* out_w   = (const float*)d_in[7];
  const float* out_b   = (const float*)d_in[8];
  const float* pos_bias = (const float*)d_in[9];
  const float* if_gain  = (const float*)d_in[10];
  float* out = (float*)d_out;
  char* ws = (char*)d_ws;

  // workspace layout (bytes)
  u16*   xbf      = (u16*)(ws + 0);              //  8,388,608 (dead after gemm)
  u16*   qbf      = (u16*)(ws + 8388608);        //  8,388,608
  u16*   kbf      = (u16*)(ws + 16777216);       //  8,388,608
  u16*   vbf      = (u16*)(ws + 25165824);       //  8,388,608 (dead after v-T)
  u16*   vbfT     = (u16*)(ws + 33554432);       //  8,388,608
  u16*   gate_buf = (u16*)(ws + 41943040);       //  8,388,608
  u16*   Cbuf     = (u16*)(ws + 50331648);       // 33,554,432 (dead after pack)
  u16*   fused_wt = (u16*)(ws + 83886080);       //  2,097,152
  u16*   out_wt   = (u16*)(ws + 85983232);       //    524,288
  float* bias_tab = (float*)(ws + 86507520);     //     65,536
  // aliases (stream-ordered safe):
  u16*   attn_buf = vbf;                         // vbf dead after transpose_v
  u16*   partO = (u16*)(ws + 0);                 // xbf dead after gemm_fused
  float* partM = (float*)(ws + 6291456);
  float* partL = (float*)(ws + 6488064);

  // prep
  cvt_bf16_kernel<<<dim3(2048), dim3(256), 0, stream>>>(
      x, xbf, BATCH * NSEQ * DMODEL / 8);
  transpose_w_kernel<<<dim3(48, 16), dim3(256), 0, stream>>>(
      qkv_w, fused_wt, DMODEL, 3 * DMODEL);
  transpose_w_kernel<<<dim3(16, 16), dim3(256), 0, stream>>>(
      gate_w, fused_wt + (size_t)3 * DMODEL * DMODEL, DMODEL, DMODEL);
  transpose_w_kernel<<<dim3(16, 16), dim3(256), 0, stream>>>(
      out_w, out_wt, DMODEL, DMODEL);
  bias_tab_kernel<<<dim3(8), dim3(256), 0, stream>>>(pos_bias, bias_tab);

  // fused qkv+gate GEMM -> C (clean coalesced epilogue)
  gemm_fused<<<dim3(16, 64), dim3(256), 0, stream>>>(
      xbf, fused_wt, qkv_b, gate_b, Cbuf);

  // pack C -> q/k/v/gate (streaming, coalesced)
  pack_kernel<<<dim3(8192), dim3(256), 0, stream>>>(
      Cbuf, k_delta, v_delta, qbf, kbf, vbf, gate_buf);

  // v -> v^T
  transpose_v_kernel<<<dim3(32, 32), dim3(256), 0, stream>>>(vbf, vbfT);

  // flash attention: split-KV balanced chunks
  attn_kernel<<<dim3(1536), dim3(256), 0, stream>>>(
      qbf, kbf, vbfT, bias_tab, if_gain, gate_buf, attn_buf,
      partO, partM, partL);

  // merge h0/h1 partials
  combine_kernel<<<dim3(128), dim3(256), 0, stream>>>(
      partO, partM, partL, if_gain, gate_buf, attn_buf);

  // final GEMM -> d_out (fp32)
  gemm_out<<<dim3(4, 128), dim3(256), 0, stream>>>(
      attn_buf, out_wt, out_b, out);

  (void)in_sizes; (void)n_in; (void)out_size; (void)ws_size;
}

// Round 9
// 102.560 us; speedup vs baseline: 1.3405x; 1.1208x over previous
//
#include <hip/hip_runtime.h>
#include <cmath>

typedef unsigned short u16;
typedef unsigned short u16x4 __attribute__((ext_vector_type(4)));
typedef unsigned short u16x8 __attribute__((ext_vector_type(8)));
typedef __bf16 bf16x8 __attribute__((ext_vector_type(8)));
typedef float f32x4 __attribute__((ext_vector_type(4)));

#define HNUM 8
#define HDIM 64
#define BATCH 4
#define NSEQ 2048
#define DMODEL 512
#define NFUSED 2048
#define LP 72    // padded LDS row stride (u16) for attn
#define CP 132   // padded C-tile row stride (u16) in gemm epilogue

__device__ __forceinline__ u16 f2bf(float f) {
  unsigned int u = __builtin_bit_cast(unsigned int, f);
  u += 0x7fffu + ((u >> 16) & 1u);          // round-to-nearest-even
  return (u16)(u >> 16);
}

__device__ __forceinline__ float bf2f(u16 v) {
  unsigned int u = ((unsigned int)v) << 16;
  return __builtin_bit_cast(float, u);
}

__device__ __forceinline__ f32x4 mfma_bf16(u16x8 a, u16x8 b, f32x4 c) {
  return __builtin_amdgcn_mfma_f32_16x16x32_bf16(
      __builtin_bit_cast(bf16x8, a), __builtin_bit_cast(bf16x8, b), c, 0, 0, 0);
}

// async global->LDS, 16 B per lane (dest must be wave-uniform base + lane*16)
__device__ __forceinline__ void gload16(u16* lds, const u16* g) {
  __builtin_amdgcn_global_load_lds(
      (const __attribute__((address_space(1))) void*)g,
      (__attribute__((address_space(3))) void*)lds, 16, 0, 0);
}

// stage a ROWS x 32 bf16 tile (row stride DMODEL) into linear LDS
template <int ROWS>
__device__ __forceinline__ void stage_tile(u16* lds, const u16* g, int tid) {
  #pragma unroll
  for (int i = 0; i < ROWS / 64; ++i) {
    const int off = (i * 256 + tid) * 8;
    const int row = off >> 5, col = off & 31;
    gload16(lds + off, g + (size_t)row * DMODEL + col);
  }
}

// ---------------------------------------------------------------------------
// Prep: fp32 -> bf16 convert (x), 8 elems/thread
// ---------------------------------------------------------------------------
__global__ __launch_bounds__(256) void cvt_bf16_kernel(
    const float* __restrict__ in, u16* __restrict__ out, int n8) {
  int i = blockIdx.x * 256 + threadIdx.x;
  if (i >= n8) return;
  const float4 f0 = *(const float4*)(in + i * 8);
  const float4 f1 = *(const float4*)(in + i * 8 + 4);
  u16x8 pk;
  pk[0] = f2bf(f0.x); pk[1] = f2bf(f0.y); pk[2] = f2bf(f0.z); pk[3] = f2bf(f0.w);
  pk[4] = f2bf(f1.x); pk[5] = f2bf(f1.y); pk[6] = f2bf(f1.z); pk[7] = f2bf(f1.w);
  *(u16x8*)(out + i * 8) = pk;
}

// ---------------------------------------------------------------------------
// Prep: W[K][N] fp32 -> Wt[N][K] bf16 (32x32 LDS tile transpose)
// ---------------------------------------------------------------------------
__global__ __launch_bounds__(256) void transpose_w_kernel(
    const float* __restrict__ W, u16* __restrict__ Wt, int K, int N) {
  __shared__ float tile[32][33];
  const int n0 = blockIdx.x * 32, k0 = blockIdx.y * 32;
  const int tx = threadIdx.x & 31, ty = threadIdx.x >> 5;
  #pragma unroll
  for (int yy = ty; yy < 32; yy += 8)
    tile[yy][tx] = W[(size_t)(k0 + yy) * N + n0 + tx];
  __syncthreads();
  #pragma unroll
  for (int yy = ty; yy < 32; yy += 8)
    Wt[(size_t)(n0 + yy) * K + k0 + tx] = f2bf(tile[tx][yy]);
}

// ---------------------------------------------------------------------------
// Prep: vbf[b,h,n,d] -> vbfT[b,h,d,n] (64x64 LDS tile transpose)
// ---------------------------------------------------------------------------
__global__ __launch_bounds__(256) void transpose_v_kernel(
    const u16* __restrict__ v, u16* __restrict__ vT) {
  __shared__ u16 t[64][LP];
  const int n0 = blockIdx.x * 64;
  const size_t bh = blockIdx.y;
  const int r = threadIdx.x >> 2, c0 = (threadIdx.x & 3) << 4;
  const u16* src = v + (bh * NSEQ + n0 + r) * HDIM + c0;
  u16x8 a0 = *(const u16x8*)src;
  u16x8 a1 = *(const u16x8*)(src + 8);
  #pragma unroll
  for (int j = 0; j < 8; ++j) {
    t[c0 + j][r] = a0[j];
    t[c0 + 8 + j][r] = a1[j];
  }
  __syncthreads();
  u16x8 o0 = *(const u16x8*)&t[r][c0];
  u16x8 o1 = *(const u16x8*)&t[r][c0 + 8];
  u16* dst = vT + (bh * HDIM + r) * NSEQ + n0 + c0;
  *(u16x8*)dst = o0;
  *(u16x8*)(dst + 8) = o1;
}

// ---------------------------------------------------------------------------
// Bias table: tab[h][d] = in_band(bucket(d),h) ? pos_bias[bucket(d)][h] : -100
// ---------------------------------------------------------------------------
__global__ __launch_bounds__(256) void bias_tab_kernel(
    const float* __restrict__ pos_bias, float* __restrict__ tab) {
  int d = blockIdx.x * 256 + threadIdx.x;   // 0..2047
  if (d >= NSEQ) return;
  int bkt;
  if (d < 28) {
    bkt = d;
  } else {
    double t = log((double)d / 28.0) / log(2048.0 / 28.0) * 16.0;
    int ti = 28 + (int)t;
    bkt = ti < 43 ? ti : 43;
  }
  const int lo[8] = {38, 34, 28, 20, 13, 7, 3, 0};
  const int hi[8] = {44, 40, 35, 28, 21, 14, 9, 6};
  #pragma unroll
  for (int h = 0; h < HNUM; ++h) {
    bool inb = (bkt >= lo[h]) && (bkt < hi[h]);
    tab[h * NSEQ + d] = inb ? pos_bias[bkt * HNUM + h] : -100.0f;
  }
}

// ---------------------------------------------------------------------------
// Fused qkv+gate GEMM with packed epilogue. 128x128 tile, BK=32, 3-deep
// pipeline with counted vmcnt (T4): stage k+2 -> vmcnt(8) -> raw barrier ->
// ds_read(k) -> lgkmcnt(0) -> 16 MFMA -> raw barrier. XCD-swizzled blocks.
// Epilogue: acc+bias -> padded LDS C-tile -> DIRECT packed coalesced writes:
//   seg0: q*0.125 | seg1: k+kdelta | seg2: v+vdelta | seg3: sigmoid gate.
// ---------------------------------------------------------------------------
__global__ __launch_bounds__(256) void gemm_fused(
    const u16* __restrict__ Abf, const u16* __restrict__ Wt,
    const float* __restrict__ qkv_b, const float* __restrict__ gate_b,
    const float* __restrict__ kdelta, const float* __restrict__ vdelta,
    u16* __restrict__ qbf, u16* __restrict__ kbf, u16* __restrict__ vbf,
    u16* __restrict__ gate) {
  __shared__ __align__(16) u16 S[6][128 * 32];   // A: S[0..2], B: S[3..5]

  // XCD swizzle: each XCD owns a contiguous band of 128 blocks (8 m-tiles)
  const int bid = blockIdx.y * 16 + blockIdx.x;
  const int nb = (bid & 7) * 128 + (bid >> 3);
  const int m0 = (nb >> 4) * 128;
  const int n0 = (nb & 15) * 128;

  const int tid = threadIdx.x;
  const int w = tid >> 6, l = tid & 63, li = l & 15, lg = l >> 4;
  const int wr = w >> 1, wc = w & 1;

  f32x4 acc[4][4];
  #pragma unroll
  for (int i = 0; i < 4; ++i)
    #pragma unroll
    for (int j = 0; j < 4; ++j) acc[i][j] = f32x4{0.f, 0.f, 0.f, 0.f};

  const u16* Ab = Abf + (size_t)m0 * DMODEL;
  const u16* Bb = Wt + (size_t)n0 * DMODEL;

  // prologue: tiles 0 and 1 in flight (8 loads/wave)
  stage_tile<128>(S[0], Ab, tid);
  stage_tile<128>(S[3], Bb, tid);
  stage_tile<128>(S[1], Ab + 32, tid);
  stage_tile<128>(S[4], Bb + 32, tid);

  #pragma unroll
  for (int kt = 0; kt < 16; ++kt) {
    if (kt + 2 < 16) {
      stage_tile<128>(S[(kt + 2) % 3], Ab + (kt + 2) * 32, tid);
      stage_tile<128>(S[3 + (kt + 2) % 3], Bb + (kt + 2) * 32, tid);
    }
    // drain exactly tile kt's 4 loads; keep newer tiles in flight
    if (kt < 14)       asm volatile("s_waitcnt vmcnt(8)" ::: "memory");
    else if (kt == 14) asm volatile("s_waitcnt vmcnt(4)" ::: "memory");
    else               asm volatile("s_waitcnt vmcnt(0)" ::: "memory");
    __builtin_amdgcn_s_barrier();            // tile kt ready in LDS
    __builtin_amdgcn_sched_barrier(0);
    const u16* Asb = S[kt % 3];
    const u16* Bsb = S[3 + kt % 3];
    u16x8 af[4], bfr[4];
    #pragma unroll
    for (int mt = 0; mt < 4; ++mt)
      af[mt] = *(const u16x8*)&Asb[(wr * 64 + mt * 16 + li) * 32 + lg * 8];
    #pragma unroll
    for (int nt = 0; nt < 4; ++nt)
      bfr[nt] = *(const u16x8*)&Bsb[(wc * 64 + nt * 16 + li) * 32 + lg * 8];
    asm volatile("s_waitcnt lgkmcnt(0)" ::: "memory");
    __builtin_amdgcn_sched_barrier(0);
    #pragma unroll
    for (int mt = 0; mt < 4; ++mt)
      #pragma unroll
      for (int nt = 0; nt < 4; ++nt)
        acc[mt][nt] = mfma_bf16(af[mt], bfr[nt], acc[mt][nt]);
    __builtin_amdgcn_s_barrier();            // release buffer kt for reuse
    __builtin_amdgcn_sched_barrier(0);
  }

  // ---- epilogue: acc+bias -> padded LDS C-tile ----
  u16* Ct = S[0];                            // ~33 KB of the 48 KB, now free
  const int seg = n0 >> 9;                   // 0=q 1=k 2=v 3=gate (uniform)
  #pragma unroll
  for (int nt = 0; nt < 4; ++nt) {
    const int col = wc * 64 + nt * 16 + li;
    const int colg = n0 + col;
    const float bv = (seg < 3) ? qkv_b[colg] : gate_b[colg & 511];
    #pragma unroll
    for (int mt = 0; mt < 4; ++mt) {
      const int row = wr * 64 + mt * 16 + lg * 4;
      #pragma unroll
      for (int r = 0; r < 4; ++r)
        Ct[(row + r) * CP + col] = f2bf(acc[mt][nt][r] + bv);
    }
  }
  __syncthreads();

  // ---- packed coalesced writes from LDS ----
  const int nin = n0 & 511;
  #pragma unroll
  for (int p = 0; p < 8; ++p) {
    const int row = p * 16 + (tid >> 4);
    const int cc = (tid & 15) * 8;
    const int rg = m0 + row;
    const int b = rg >> 11, n = rg & 2047;
    u16x8 cv = *(const u16x8*)&Ct[row * CP + cc];
    if (seg == 3) {
      u16x8 o;
      #pragma unroll
      for (int j = 0; j < 8; ++j)
        o[j] = f2bf(1.f / (1.f + __expf(-bf2f(cv[j]))));
      *(u16x8*)&gate[(size_t)rg * DMODEL + nin + cc] = o;
    } else {
      const int hh = (nin + cc) >> 6, hd = (nin + cc) & 63;
      const size_t hidx = (((size_t)b * HNUM + hh) * NSEQ + n) * HDIM + hd;
      if (seg == 0) {
        u16x8 o;
        #pragma unroll
        for (int j = 0; j < 8; ++j) o[j] = f2bf(bf2f(cv[j]) * 0.125f);
        *(u16x8*)&qbf[hidx] = o;
      } else {
        const float* dp = (seg == 1 ? kdelta : vdelta) + hidx;
        float4 d0 = *(const float4*)dp;
        float4 d1 = *(const float4*)(dp + 4);
        u16x8 o;
        o[0] = f2bf(bf2f(cv[0]) + d0.x); o[1] = f2bf(bf2f(cv[1]) + d0.y);
        o[2] = f2bf(bf2f(cv[2]) + d0.z); o[3] = f2bf(bf2f(cv[3]) + d0.w);
        o[4] = f2bf(bf2f(cv[4]) + d1.x); o[5] = f2bf(bf2f(cv[5]) + d1.y);
        o[6] = f2bf(bf2f(cv[6]) + d1.z); o[7] = f2bf(bf2f(cv[7]) + d1.w);
        *(u16x8*)&((seg == 1) ? kbf : vbf)[hidx] = o;
      }
    }
  }
}

// ---------------------------------------------------------------------------
// Out GEMM: [8192,512]bf16 @ out_wt[512,512]^T + out_b -> fp32. 64x128 tile,
// BK=32, 2-phase static-dbuf pipeline. Grid (4,128) = 512 blocks.
// ---------------------------------------------------------------------------
__global__ __launch_bounds__(256) void gemm_out(
    const u16* __restrict__ Abf, const u16* __restrict__ Wt,
    const float* __restrict__ bias, float* __restrict__ outf) {
  __shared__ __align__(16) u16 As0[64 * 32];
  __shared__ __align__(16) u16 As1[64 * 32];
  __shared__ __align__(16) u16 Bs0[128 * 32];
  __shared__ __align__(16) u16 Bs1[128 * 32];

  const int m0 = blockIdx.y * 64, n0 = blockIdx.x * 128;
  const int tid = threadIdx.x;
  const int w = tid >> 6, l = tid & 63, li = l & 15, lg = l >> 4;
  const int wr = w >> 1, wc = w & 1;

  f32x4 acc[2][4];
  #pragma unroll
  for (int i = 0; i < 2; ++i)
    #pragma unroll
    for (int j = 0; j < 4; ++j) acc[i][j] = f32x4{0.f, 0.f, 0.f, 0.f};

  const u16* Ab = Abf + (size_t)m0 * DMODEL;
  const u16* Bb = Wt + (size_t)n0 * DMODEL;

  auto compute = [&](const u16* Asb, const u16* Bsb) {
    u16x8 af[2], bfr[4];
    #pragma unroll
    for (int mt = 0; mt < 2; ++mt)
      af[mt] = *(const u16x8*)&Asb[(wr * 32 + mt * 16 + li) * 32 + lg * 8];
    #pragma unroll
    for (int nt = 0; nt < 4; ++nt)
      bfr[nt] = *(const u16x8*)&Bsb[(wc * 64 + nt * 16 + li) * 32 + lg * 8];
    asm volatile("s_waitcnt lgkmcnt(0)" ::: "memory");
    __builtin_amdgcn_sched_barrier(0);
    #pragma unroll
    for (int mt = 0; mt < 2; ++mt)
      #pragma unroll
      for (int nt = 0; nt < 4; ++nt)
        acc[mt][nt] = mfma_bf16(af[mt], bfr[nt], acc[mt][nt]);
  };

  stage_tile<64>(As0, Ab, tid);
  stage_tile<128>(Bs0, Bb, tid);
  asm volatile("s_waitcnt vmcnt(0)" ::: "memory");
  __syncthreads();

  #pragma unroll 1
  for (int kt2 = 0; kt2 < 8; ++kt2) {
    {
      const int kn = kt2 * 2 + 1;
      if (kn < 16) {
        stage_tile<64>(As1, Ab + kn * 32, tid);
        stage_tile<128>(Bs1, Bb + kn * 32, tid);
      }
      compute(As0, Bs0);
      asm volatile("s_waitcnt vmcnt(0)" ::: "memory");
      __syncthreads();
    }
    {
      const int kn = kt2 * 2 + 2;
      if (kn < 16) {
        stage_tile<64>(As0, Ab + kn * 32, tid);
        stage_tile<128>(Bs0, Bb + kn * 32, tid);
      }
      compute(As1, Bs1);
      asm volatile("s_waitcnt vmcnt(0)" ::: "memory");
      __syncthreads();
    }
  }

  #pragma unroll
  for (int nt = 0; nt < 4; ++nt) {
    const int colg = n0 + wc * 64 + nt * 16 + li;
    const float bv = bias[colg];
    #pragma unroll
    for (int mt = 0; mt < 2; ++mt) {
      #pragma unroll
      for (int r = 0; r < 4; ++r) {
        const int rowg = m0 + wr * 32 + mt * 16 + lg * 4 + r;
        outf[(size_t)rowg * DMODEL + colg] = acc[mt][nt][r] + bv;
      }
    }
  }
}

// ---------------------------------------------------------------------------
// Flash attention, swapped-QK^T, banded KV windows, split-KV balanced chunks.
// (verified round-5..8 body, unchanged)
// ---------------------------------------------------------------------------
__global__ __launch_bounds__(256) void attn_kernel(
    const u16* __restrict__ qbf, const u16* __restrict__ kbf,
    const u16* __restrict__ vbfT, const float* __restrict__ bias_tab,
    const float* __restrict__ if_gain, const u16* __restrict__ gate,
    u16* __restrict__ attn_out, u16* __restrict__ partO,
    float* __restrict__ partM, float* __restrict__ partL) {
  __shared__ __align__(16) u16 Ks[64][LP];   // [kv][hd]
  __shared__ __align__(16) u16 Vt[64][LP];   // [hd][kv]
  __shared__ __align__(16) u16 Pl[4][16][LP];

  static const int DMINW[8] = {408, 139, 26, 18, 11, 5, 1, 0};
  static const int DMAXW[8] = {2049, 702, 185, 29, 22, 15, 10, 7};
  static const int DMINS[8] = {412, 143, 30, 22, 15, 9, 5, 2};
  static const int SH[12] = {0, 0, 0, 0, 1, 1, 2, 3, 4, 5, 6, 7};
  static const int SC[12] = {0, 1, 2, 3, 0, 1, 0, 0, 0, 0, 0, 0};
  static const int SN[12] = {4, 4, 4, 4, 2, 2, 1, 1, 1, 1, 1, 1};

  const int slot = blockIdx.x >> 7;
  const int rem = blockIdx.x & 127;
  const int qt = 31 - (rem >> 2);
  const int b = rem & 3;
  const int h = SH[slot], ch = SC[slot], nc = SN[slot];
  const int bh = b * HNUM + h;
  const int q0 = qt * 64;
  const int tid = threadIdx.x;
  const int w = tid >> 6, l = tid & 63, li = l & 15, lg = l >> 4;

  const u16* qrow = qbf + ((size_t)bh * NSEQ + q0 + w * 16 + li) * HDIM;
  u16x8 qf0 = *(const u16x8*)(qrow + lg * 8);
  u16x8 qf1 = *(const u16x8*)(qrow + 32 + lg * 8);

  const bool pure = q0 >= DMINS[h];
  int kv_lo = 0, kv_hi = q0 + 64;
  if (pure) {
    int lo = q0 - DMAXW[h];
    kv_lo = (lo > 0 ? lo : 0) & ~63;
    kv_hi = q0 + 64 - DMINW[h];
  }
  const int t0 = kv_lo >> 6, t1 = (kv_hi - 1) >> 6;
  const int len = t1 - t0 + 1;
  const int ta = t0 + (len * ch) / nc;
  const int tb = t0 + (len * (ch + 1)) / nc - 1;

  const int srow = tid >> 2;
  const int scb = (tid & 3) << 4;
  const float* btab = bias_tab + h * NSEQ;

  float mrun = -INFINITY, lrun = 0.f;
  f32x4 O[4] = {{0.f,0.f,0.f,0.f},{0.f,0.f,0.f,0.f},
                {0.f,0.f,0.f,0.f},{0.f,0.f,0.f,0.f}};

  for (int tt = ta; tt <= tb; ++tt) {
    const int kv0 = tt << 6;
    {
      const size_t kbase = ((size_t)bh * NSEQ + kv0 + srow) * HDIM + scb;
      u16x8 k0 = *(const u16x8*)(kbf + kbase);
      u16x8 k1 = *(const u16x8*)(kbf + kbase + 8);
      const size_t vbase = ((size_t)bh * HDIM + srow) * NSEQ + kv0 + scb;
      u16x8 v0 = *(const u16x8*)(vbfT + vbase);
      u16x8 v1 = *(const u16x8*)(vbfT + vbase + 8);
      *(u16x8*)&Ks[srow][scb] = k0;
      *(u16x8*)&Ks[srow][scb + 8] = k1;
      *(u16x8*)&Vt[srow][scb] = v0;
      *(u16x8*)&Vt[srow][scb + 8] = v1;
    }
    __syncthreads();

    f32x4 s[4];
    #pragma unroll
    for (int t = 0; t < 4; ++t) {
      u16x8 a0 = *(const u16x8*)&Ks[t * 16 + li][lg * 8];
      u16x8 a1 = *(const u16x8*)&Ks[t * 16 + li][32 + lg * 8];
      f32x4 acc = {0.f, 0.f, 0.f, 0.f};
      acc = mfma_bf16(a0, qf0, acc);
      acc = mfma_bf16(a1, qf1, acc);
      s[t] = acc;
    }

    const int D0 = (q0 + w * 16 + li) - kv0 - lg * 4;
    float rm = -1e30f;
    #pragma unroll
    for (int t = 0; t < 4; ++t) {
      #pragma unroll
      for (int r = 0; r < 4; ++r) {
        int d = D0 - 16 * t - r;
        float sv = s[t][r];
        sv = (d >= 0) ? (sv + btab[d]) : -1e30f;
        s[t][r] = sv;
        rm = fmaxf(rm, sv);
      }
    }
    rm = fmaxf(rm, __shfl_xor(rm, 16, 64));
    rm = fmaxf(rm, __shfl_xor(rm, 32, 64));
    const float mn = fmaxf(mrun, rm);
    const float f = __expf(mrun - mn);
    mrun = mn;
    float ps = 0.f;
    #pragma unroll
    for (int t = 0; t < 4; ++t) {
      #pragma unroll
      for (int r = 0; r < 4; ++r) {
        float p = __expf(s[t][r] - mn);
        s[t][r] = p;
        ps += p;
      }
    }
    ps += __shfl_xor(ps, 16, 64);
    ps += __shfl_xor(ps, 32, 64);
    lrun = lrun * f + ps;

    #pragma unroll
    for (int t = 0; t < 4; ++t) {
      u16x4 pk;
      pk[0] = f2bf(s[t][0]); pk[1] = f2bf(s[t][1]);
      pk[2] = f2bf(s[t][2]); pk[3] = f2bf(s[t][3]);
      *(u16x4*)&Pl[w][li][t * 16 + lg * 4] = pk;
    }

    float fr[4];
    #pragma unroll
    for (int r = 0; r < 4; ++r) fr[r] = __shfl(f, lg * 4 + r, 64);
    #pragma unroll
    for (int dt = 0; dt < 4; ++dt) {
      O[dt][0] *= fr[0]; O[dt][1] *= fr[1];
      O[dt][2] *= fr[2]; O[dt][3] *= fr[3];
    }
    __syncthreads();

    #pragma unroll
    for (int ks = 0; ks < 2; ++ks) {
      u16x8 pA = *(const u16x8*)&Pl[w][li][ks * 32 + lg * 8];
      #pragma unroll
      for (int dt = 0; dt < 4; ++dt) {
        u16x8 vB = *(const u16x8*)&Vt[dt * 16 + li][ks * 32 + lg * 8];
        O[dt] = mfma_bf16(pA, vB, O[dt]);
      }
    }
    __syncthreads();
  }

  if (nc == 1) {
    const float gain = if_gain[h];
    float linv[4];
    #pragma unroll
    for (int r = 0; r < 4; ++r)
      linv[r] = gain / __shfl(lrun, lg * 4 + r, 64);
    #pragma unroll
    for (int r = 0; r < 4; ++r) {
      const int i = q0 + w * 16 + lg * 4 + r;
      const size_t base = ((size_t)b * NSEQ + i) * DMODEL + h * HDIM + li;
      #pragma unroll
      for (int dt = 0; dt < 4; ++dt) {
        const float g = bf2f(gate[base + dt * 16]);
        attn_out[base + dt * 16] = f2bf(O[dt][r] * linv[r] * g);
      }
    }
  } else {
    const int sbase = (b * 32 + qt) * 6 + slot;   // slot in 0..5 here
    #pragma unroll
    for (int r = 0; r < 4; ++r) {
      const int rl = w * 16 + lg * 4 + r;
      #pragma unroll
      for (int dt = 0; dt < 4; ++dt)
        partO[(size_t)sbase * 4096 + rl * 64 + dt * 16 + li] = f2bf(O[dt][r]);
    }
    if (lg == 0) {
      partM[sbase * 64 + w * 16 + li] = mrun;
      partL[sbase * 64 + w * 16 + li] = lrun;
    }
  }
}

// ---------------------------------------------------------------------------
// Combine split-KV partials for h0 (4 chunks) and h1 (2 chunks).
// ---------------------------------------------------------------------------
__global__ __launch_bounds__(256) void combine_kernel(
    const u16* __restrict__ partO, const float* __restrict__ partM,
    const float* __restrict__ partL, const float* __restrict__ if_gain,
    const u16* __restrict__ gate, u16* __restrict__ attn_out) {
  const int b = blockIdx.x & 3, qt = blockIdx.x >> 2;
  const int tid = threadIdx.x;
  const int row = tid >> 2, d0 = (tid & 3) << 4;

  #pragma unroll
  for (int hc = 0; hc < 2; ++hc) {
    const int nc = hc ? 2 : 4, s0 = hc ? 4 : 0;
    const int sbase = (b * 32 + qt) * 6 + s0;
    float m[4], wch[4];
    float M = -INFINITY;
    #pragma unroll
    for (int c = 0; c < 4; ++c) {
      m[c] = (c < nc) ? partM[(sbase + c) * 64 + row] : -INFINITY;
      M = fmaxf(M, m[c]);
    }
    float den = 0.f;
    #pragma unroll
    for (int c = 0; c < 4; ++c) {
      wch[c] = (c < nc) ? __expf(m[c] - M) : 0.f;
      if (c < nc) den += wch[c] * partL[(sbase + c) * 64 + row];
    }
    float num[16];
    #pragma unroll
    for (int j = 0; j < 16; ++j) num[j] = 0.f;
    #pragma unroll
    for (int c = 0; c < 4; ++c) {
      if (c < nc) {
        const u16* op = partO + (size_t)(sbase + c) * 4096 + row * 64 + d0;
        u16x8 o0 = *(const u16x8*)op;
        u16x8 o1 = *(const u16x8*)(op + 8);
        #pragma unroll
        for (int j = 0; j < 8; ++j) {
          num[j]     += wch[c] * bf2f(o0[j]);
          num[8 + j] += wch[c] * bf2f(o1[j]);
        }
      }
    }
    const float inv = if_gain[hc] / den;
    const size_t obase =
        ((size_t)b * NSEQ + qt * 64 + row) * DMODEL + hc * HDIM + d0;
    u16x8 g0 = *(const u16x8*)(gate + obase);
    u16x8 g1 = *(const u16x8*)(gate + obase + 8);
    u16x8 r0, r1;
    #pragma unroll
    for (int j = 0; j < 8; ++j) {
      r0[j] = f2bf(num[j] * inv * bf2f(g0[j]));
      r1[j] = f2bf(num[8 + j] * inv * bf2f(g1[j]));
    }
    *(u16x8*)(attn_out + obase) = r0;
    *(u16x8*)(attn_out + obase + 8) = r1;
  }
}

// ---------------------------------------------------------------------------
extern "C" void kernel_launch(void* const* d_in, const int* in_sizes, int n_in,
                              void* d_out, int out_size, void* d_ws,
                              size_t ws_size, hipStream_t stream) {
  const float* x       = (const float*)d_in[0];
  const float* k_delta = (const float*)d_in[1];
  const float* v_delta = (const float*)d_in[2];
  const float* qkv_w   = (const float*)d_in[3];
  const float* qkv_b   = (const float*)d_in[4];
  const float* gate_w  = (const float*)d_in[5];
  const float* gate_b  = (const float*)d_in[6];
  const float* out_w   = (const float*)d_in[7];
  const float* out_b   = (const float*)d_in[8];
  const float* pos_bias = (const float*)d_in[9];
  const float* if_gain  = (const float*)d_in[10];
  float* out = (float*)d_out;
  char* ws = (char*)d_ws;

  // workspace layout (bytes)
  u16*   xbf      = (u16*)(ws + 0);              //  8,388,608 (dead after gemm)
  u16*   qbf      = (u16*)(ws + 8388608);        //  8,388,608
  u16*   kbf      = (u16*)(ws + 16777216);       //  8,388,608
  u16*   vbf      = (u16*)(ws + 25165824);       //  8,388,608 (dead after v-T)
  u16*   vbfT     = (u16*)(ws + 33554432);       //  8,388,608
  u16*   gate_buf = (u16*)(ws + 41943040);       //  8,388,608
  u16*   fused_wt = (u16*)(ws + 50331648);       //  2,097,152
  u16*   out_wt   = (u16*)(ws + 52428800);       //    524,288
  float* bias_tab = (float*)(ws + 52953088);     //     65,536
  // aliases (stream-ordered safe):
  u16*   attn_buf = vbf;                         // vbf dead after transpose_v
  u16*   partO = (u16*)(ws + 0);                 // xbf dead after gemm_fused
  float* partM = (float*)(ws + 6291456);
  float* partL = (float*)(ws + 6488064);

  // prep
  cvt_bf16_kernel<<<dim3(2048), dim3(256), 0, stream>>>(
      x, xbf, BATCH * NSEQ * DMODEL / 8);
  transpose_w_kernel<<<dim3(48, 16), dim3(256), 0, stream>>>(
      qkv_w, fused_wt, DMODEL, 3 * DMODEL);
  transpose_w_kernel<<<dim3(16, 16), dim3(256), 0, stream>>>(
      gate_w, fused_wt + (size_t)3 * DMODEL * DMODEL, DMODEL, DMODEL);
  transpose_w_kernel<<<dim3(16, 16), dim3(256), 0, stream>>>(
      out_w, out_wt, DMODEL, DMODEL);
  bias_tab_kernel<<<dim3(8), dim3(256), 0, stream>>>(pos_bias, bias_tab);

  // fused qkv+gate GEMM with packed epilogue (q/k/v/gate written directly)
  gemm_fused<<<dim3(16, 64), dim3(256), 0, stream>>>(
      xbf, fused_wt, qkv_b, gate_b, k_delta, v_delta,
      qbf, kbf, vbf, gate_buf);

  // v -> v^T
  transpose_v_kernel<<<dim3(32, 32), dim3(256), 0, stream>>>(vbf, vbfT);

  // flash attention: split-KV balanced chunks
  attn_kernel<<<dim3(1536), dim3(256), 0, stream>>>(
      qbf, kbf, vbfT, bias_tab, if_gain, gate_buf, attn_buf,
      partO, partM, partL);

  // merge h0/h1 partials
  combine_kernel<<<dim3(128), dim3(256), 0, stream>>>(
      partO, partM, partL, if_gain, gate_buf, attn_buf);

  // final GEMM -> d_out (fp32)
  gemm_out<<<dim3(4, 128), dim3(256), 0, stream>>>(
      attn_buf, out_wt, out_b, out);

  (void)in_sizes; (void)n_in; (void)out_size; (void)ws_size;
}